// Round 1
// baseline (964.753 us; speedup 1.0000x reference)
//
#include <hip/hip_runtime.h>
#include <hip/hip_bf16.h>
#include <math.h>

#define NN 50000
#define NM 10000
#define NE 400000
#define CD 256
#define NH 8
#define NF 32
#define C2 16
#define MAXD 1024

#define CDIV(a,b) (((a)+(b)-1)/(b))

// ---------------- CSR build ----------------

__global__ void count_deg_kernel(const int* __restrict__ node_idx, const int* __restrict__ hedge_idx,
                                 int* __restrict__ deg_node, int* __restrict__ deg_hedge) {
    int e = blockIdx.x * 256 + threadIdx.x;
    if (e < NE) {
        atomicAdd(&deg_node[node_idx[e]], 1);
        atomicAdd(&deg_hedge[hedge_idx[e]], 1);
    }
}

__global__ __launch_bounds__(1024) void scan_kernel(const int* __restrict__ deg, int* __restrict__ off, int n) {
    __shared__ int lds[1024];
    __shared__ int carry_s;
    int t = threadIdx.x;
    if (t == 0) carry_s = 0;
    __syncthreads();
    for (int start = 0; start < n; start += 1024) {
        int i = start + t;
        int v = (i < n) ? deg[i] : 0;
        lds[t] = v;
        __syncthreads();
        for (int s = 1; s < 1024; s <<= 1) {
            int tv = (t >= s) ? lds[t - s] : 0;
            __syncthreads();
            lds[t] += tv;
            __syncthreads();
        }
        int carry = carry_s;
        if (i < n) off[i] = carry + lds[t] - v;
        int total = lds[1023];
        __syncthreads();
        if (t == 0) carry_s = carry + total;
        __syncthreads();
    }
    if (t == 0) off[n] = carry_s;
}

__global__ void fill_kernel(const int* __restrict__ node_idx, const int* __restrict__ hedge_idx,
                            const int* __restrict__ node_off, const int* __restrict__ hedge_off,
                            int* __restrict__ cnt_node, int* __restrict__ cnt_hedge,
                            int* __restrict__ node_inc, int* __restrict__ hedge_inc) {
    int e = blockIdx.x * 256 + threadIdx.x;
    if (e < NE) {
        int n = node_idx[e];
        int p = node_off[n] + atomicAdd(&cnt_node[n], 1);
        node_inc[p] = e;
        int m = hedge_idx[e];
        int q = hedge_off[m] + atomicAdd(&cnt_hedge[m], 1);
        hedge_inc[q] = e;
    }
}

// ---------------- hyperedge feature sum (segment_sum of src[node_idx] by hedge) ----------------
// one block (256 threads) per hedge; thread c owns channel c
__global__ __launch_bounds__(256) void hedge_sum_kernel(const float* __restrict__ src,
        const int* __restrict__ node_idx, const int* __restrict__ inc, const int* __restrict__ offs,
        float* __restrict__ out) {
    int m = blockIdx.x;
    int beg = offs[m], end = offs[m + 1];
    int c = threadIdx.x;
    float acc = 0.0f;
    for (int i = beg; i < end; ++i) {
        int e = inc[i];
        int n = node_idx[e];
        acc += src[(size_t)n * CD + c];
    }
    out[(size_t)m * CD + c] = acc;
}

// ---------------- GEMM: C[R x 256] = A[R x 256] @ W[256 x 256] ----------------
__global__ __launch_bounds__(256) void gemm256_kernel(const float* __restrict__ A,
        const float* __restrict__ W, float* __restrict__ C, int R) {
    __shared__ float As[16][65];
    __shared__ float Ws[16][64];
    int tid = threadIdx.x;
    int tx = tid & 15, ty = tid >> 4;
    int rowBase = blockIdx.x * 64;
    int colBase = blockIdx.y * 64;
    float acc[4][4] = {};
    for (int k0 = 0; k0 < 256; k0 += 16) {
        for (int p = 0; p < 4; ++p) {
            int i = tid + p * 256;
            int r = i >> 4, k = i & 15;
            int gr = rowBase + r;
            As[k][r] = (gr < R) ? A[(size_t)gr * 256 + k0 + k] : 0.0f;
        }
        for (int p = 0; p < 4; ++p) {
            int i = tid + p * 256;
            int k = i >> 6, c = i & 63;
            Ws[k][c] = W[(size_t)(k0 + k) * 256 + colBase + c];
        }
        __syncthreads();
        for (int k = 0; k < 16; ++k) {
            float a[4], b[4];
            #pragma unroll
            for (int i = 0; i < 4; ++i) a[i] = As[k][ty * 4 + i];
            #pragma unroll
            for (int j = 0; j < 4; ++j) b[j] = Ws[k][tx * 4 + j];
            #pragma unroll
            for (int i = 0; i < 4; ++i)
                #pragma unroll
                for (int j = 0; j < 4; ++j) acc[i][j] += a[i] * b[j];
        }
        __syncthreads();
    }
    for (int i = 0; i < 4; ++i) {
        int gr = rowBase + ty * 4 + i;
        if (gr < R)
            for (int j = 0; j < 4; ++j)
                C[(size_t)gr * 256 + colBase + tx * 4 + j] = acc[i][j];
    }
}

// ---------------- GEMM small: C[R x 16] = A[R x 256] @ W[256 x 16] ----------------
__global__ __launch_bounds__(256) void gemm16_kernel(const float* __restrict__ A,
        const float* __restrict__ W, float* __restrict__ C, int R) {
    __shared__ float Ws[256 * 16];
    __shared__ float As[16][257];
    int t = threadIdx.x;
    int r0 = blockIdx.x * 16;
    for (int i = t; i < 256 * 16; i += 256) Ws[i] = W[i];
    for (int i = t; i < 16 * 256; i += 256) {
        int r = i >> 8, k = i & 255;
        As[r][k] = (r0 + r < R) ? A[(size_t)(r0 + r) * 256 + k] : 0.0f;
    }
    __syncthreads();
    int r = t >> 4, c = t & 15;
    float acc = 0.0f;
    for (int k = 0; k < 256; ++k) acc += As[r][k] * Ws[k * 16 + c];
    if (r0 + r < R) C[(size_t)(r0 + r) * 16 + c] = acc;
}

// ---------------- attention scores (8 heads, dim 32) ----------------
// one block per row; score[row,h] = dot(feats[row, h*32 : h*32+32], att[h, attOff : attOff+32])
__global__ __launch_bounds__(256) void scores8_kernel(const float* __restrict__ feats,
        const float* __restrict__ att, int attOff, float* __restrict__ out, int rows) {
    int n = blockIdx.x;
    int t = threadIdx.x;
    int h = t >> 5, f = t & 31;
    float v = feats[(size_t)n * 256 + t] * att[h * 64 + attOff + f];
    #pragma unroll
    for (int s = 16; s >= 1; s >>= 1) v += __shfl_xor(v, s);
    if (f == 0) out[(size_t)n * 8 + h] = v;
}

// ---------------- attention scores (1 head, dim 16); 16 rows per block ----------------
__global__ __launch_bounds__(256) void scores1_kernel(const float* __restrict__ feats,
        const float* __restrict__ att, int attOff, float* __restrict__ out, int rows) {
    int t = threadIdx.x;
    int r = blockIdx.x * 16 + (t >> 4);
    int c = t & 15;
    float v = 0.0f;
    if (r < rows) v = feats[(size_t)r * 16 + c] * att[attOff + c];
    #pragma unroll
    for (int s = 8; s >= 1; s >>= 1) v += __shfl_xor(v, s);
    if (r < rows && c == 0) out[r] = v;
}

// ---------------- conv1: per-hedge softmax + edge_out ----------------
__global__ __launch_bounds__(256) void hedge_attn1_kernel(const float* __restrict__ xl,
        const float* __restrict__ sn, const float* __restrict__ sh,
        const int* __restrict__ node_idx, const int* __restrict__ inc, const int* __restrict__ offs,
        float* __restrict__ alphaE, float* __restrict__ edge_out) {
    __shared__ float sc[MAXD * 8];   // 32 KB
    __shared__ int nl[MAXD];         // 4 KB
    __shared__ float shm[8];
    __shared__ float red[256];
    int m = blockIdx.x;
    int beg = offs[m], d = offs[m + 1] - beg;
    int t = threadIdx.x;
    if (t < 8) shm[t] = sh[(size_t)m * 8 + t];
    for (int i = t; i < d; i += 256) nl[i] = node_idx[inc[beg + i]];
    __syncthreads();
    // scores + leaky relu
    for (int idx = t; idx < d * 8; idx += 256) {
        int i = idx >> 3, h = idx & 7;
        float s = sn[(size_t)nl[i] * 8 + h] + shm[h];
        sc[idx] = (s > 0.0f) ? s : 0.2f * s;
    }
    __syncthreads();
    int h = t & 7, lane = t >> 3;  // lane in [0,32)
    // per-head max
    float pm = -INFINITY;
    for (int i = lane; i < d; i += 32) pm = fmaxf(pm, sc[i * 8 + h]);
    red[t] = pm;
    __syncthreads();
    for (int s2 = 16; s2 >= 1; s2 >>= 1) {
        if (lane < s2) red[t] = fmaxf(red[t], red[t + s2 * 8]);
        __syncthreads();
    }
    float mh = red[h];
    __syncthreads();
    // exp + sum
    float ps = 0.0f;
    for (int i = lane; i < d; i += 32) {
        float ev = __expf(sc[i * 8 + h] - mh);
        sc[i * 8 + h] = ev;
        ps += ev;
    }
    red[t] = ps;
    __syncthreads();
    for (int s2 = 16; s2 >= 1; s2 >>= 1) {
        if (lane < s2) red[t] += red[t + s2 * 8];
        __syncthreads();
    }
    float inv = 1.0f / (red[h] + 1e-16f);
    __syncthreads();
    // normalize + store global alpha
    for (int i = lane; i < d; i += 32) {
        float a = sc[i * 8 + h] * inv;
        sc[i * 8 + h] = a;
        alphaE[(size_t)inc[beg + i] * 8 + h] = a;
    }
    __syncthreads();
    // edge_out[m, c] = B * sum_i alpha[i, h(c)] * xl[n_i, c]
    int hh = t >> 5;
    float acc = 0.0f;
    for (int i = 0; i < d; ++i) {
        acc += sc[i * 8 + hh] * xl[(size_t)nl[i] * 256 + t];
    }
    float B = (d > 0) ? 1.0f / (float)d : 0.0f;
    edge_out[(size_t)m * 256 + t] = acc * B;
}

// ---------------- conv1: per-node aggregation + bias + relu ----------------
__global__ __launch_bounds__(256) void node_agg1_kernel(const float* __restrict__ edge_out,
        const float* __restrict__ alphaE, const int* __restrict__ hedge_idx,
        const int* __restrict__ inc, const int* __restrict__ offs,
        const float* __restrict__ b1, float* __restrict__ hout) {
    int n = blockIdx.x;
    int t = threadIdx.x;
    int beg = offs[n], end = offs[n + 1];
    int h = t >> 5;
    float acc = 0.0f;
    for (int i = beg; i < end; ++i) {
        int e = inc[i];
        int m = hedge_idx[e];
        acc += alphaE[(size_t)e * 8 + h] * edge_out[(size_t)m * 256 + t];
    }
    int d = end - beg;
    float D = (d > 0) ? 1.0f / (float)d : 0.0f;
    float v = acc * D + b1[t];
    hout[(size_t)n * 256 + t] = (v > 0.0f) ? v : 0.0f;
}

// ---------------- conv2: per-hedge softmax + edge_out (1 head, 16 ch) ----------------
__global__ __launch_bounds__(256) void hedge_attn2_kernel(const float* __restrict__ xl2,
        const float* __restrict__ sn2, const float* __restrict__ sh2,
        const int* __restrict__ node_idx, const int* __restrict__ inc, const int* __restrict__ offs,
        float* __restrict__ alpha2, float* __restrict__ edge_out2) {
    __shared__ float sc[MAXD];
    __shared__ int nl[MAXD];
    __shared__ float red[256];
    int m = blockIdx.x;
    int beg = offs[m], d = offs[m + 1] - beg;
    int t = threadIdx.x;
    float shv = sh2[m];
    for (int i = t; i < d; i += 256) {
        int e = inc[beg + i];
        int n = node_idx[e];
        nl[i] = n;
        float s = sn2[n] + shv;
        sc[i] = (s > 0.0f) ? s : 0.2f * s;
    }
    __syncthreads();
    float pm = -INFINITY;
    for (int i = t; i < d; i += 256) pm = fmaxf(pm, sc[i]);
    red[t] = pm;
    __syncthreads();
    for (int s2 = 128; s2 >= 1; s2 >>= 1) {
        if (t < s2) red[t] = fmaxf(red[t], red[t + s2]);
        __syncthreads();
    }
    float mh = red[0];
    __syncthreads();
    float ps = 0.0f;
    for (int i = t; i < d; i += 256) {
        float ev = __expf(sc[i] - mh);
        sc[i] = ev;
        ps += ev;
    }
    red[t] = ps;
    __syncthreads();
    for (int s2 = 128; s2 >= 1; s2 >>= 1) {
        if (t < s2) red[t] += red[t + s2];
        __syncthreads();
    }
    float inv = 1.0f / (red[0] + 1e-16f);
    __syncthreads();
    for (int i = t; i < d; i += 256) {
        float a = sc[i] * inv;
        sc[i] = a;
        alpha2[inc[beg + i]] = a;
    }
    __syncthreads();
    // accumulate: ip in [0,16), c in [0,16)
    int ip = t >> 4, c = t & 15;
    float acc = 0.0f;
    for (int i = ip; i < d; i += 16) acc += sc[i] * xl2[(size_t)nl[i] * 16 + c];
    red[t] = acc;
    __syncthreads();
    for (int s2 = 8; s2 >= 1; s2 >>= 1) {
        if (ip < s2) red[ip * 16 + c] += red[(ip + s2) * 16 + c];
        __syncthreads();
    }
    if (t < 16) {
        float B = (d > 0) ? 1.0f / (float)d : 0.0f;
        edge_out2[(size_t)m * 16 + t] = red[t] * B;
    }
}

// ---------------- conv2: per-node aggregation + bias + log_softmax ----------------
__global__ __launch_bounds__(64) void node_out2_kernel(const float* __restrict__ edge_out2,
        const float* __restrict__ alpha2, const int* __restrict__ hedge_idx,
        const int* __restrict__ inc, const int* __restrict__ offs,
        const float* __restrict__ b2, float* __restrict__ out) {
    int n = blockIdx.x;
    int t = threadIdx.x;   // 64
    int beg = offs[n], end = offs[n + 1];
    int ip = t >> 4, c = t & 15;
    float acc = 0.0f;
    for (int i = beg + ip; i < end; i += 4) {
        int e = inc[i];
        int m = hedge_idx[e];
        acc += alpha2[e] * edge_out2[(size_t)m * 16 + c];
    }
    acc += __shfl_xor(acc, 16);
    acc += __shfl_xor(acc, 32);
    int d = end - beg;
    float D = (d > 0) ? 1.0f / (float)d : 0.0f;
    float v = acc * D + b2[c];
    float mx = v;
    #pragma unroll
    for (int s = 8; s >= 1; s >>= 1) mx = fmaxf(mx, __shfl_xor(mx, s));
    float ex = __expf(v - mx);
    float sm = ex;
    #pragma unroll
    for (int s = 8; s >= 1; s >>= 1) sm += __shfl_xor(sm, s);
    if (t < 16) out[(size_t)n * 16 + t] = (v - mx) - logf(sm);
}

extern "C" void kernel_launch(void* const* d_in, const int* in_sizes, int n_in,
                              void* d_out, int out_size, void* d_ws, size_t ws_size,
                              hipStream_t stream) {
    const float* x        = (const float*)d_in[0];
    const int*   node_idx = (const int*)d_in[1];
    const int*   hedge_idx= (const int*)d_in[2];
    const float* W1       = (const float*)d_in[3];
    const float* att1     = (const float*)d_in[4];
    const float* b1       = (const float*)d_in[5];
    const float* W2       = (const float*)d_in[6];
    const float* att2     = (const float*)d_in[7];
    const float* b2       = (const float*)d_in[8];
    float* out = (float*)d_out;

    char* w = (char*)d_ws;
    auto carve = [&](size_t bytes) -> char* {
        char* p = w;
        w += (bytes + 255) & ~(size_t)255;
        return p;
    };
    int* deg_node  = (int*)carve((size_t)NN * 4);
    int* deg_hedge = (int*)carve((size_t)NM * 4);
    int* cnt_node  = (int*)carve((size_t)NN * 4);
    int* cnt_hedge = (int*)carve((size_t)NM * 4);
    char* zero_end = w;
    int* node_off  = (int*)carve((size_t)(NN + 1) * 4);
    int* hedge_off = (int*)carve((size_t)(NM + 1) * 4);
    int* node_inc  = (int*)carve((size_t)NE * 4);
    int* hedge_inc = (int*)carve((size_t)NE * 4);
    float* h_attr  = (float*)carve((size_t)NM * CD * 4);   // reused for conv2
    float* xl      = (float*)carve((size_t)NN * CD * 4);
    float* hl      = (float*)carve((size_t)NM * CD * 4);
    float* sn      = (float*)carve((size_t)NN * NH * 4);
    float* sh      = (float*)carve((size_t)NM * NH * 4);
    float* alphaE  = (float*)carve((size_t)NE * NH * 4);
    float* edge_out= (float*)carve((size_t)NM * CD * 4);
    float* hbuf    = (float*)carve((size_t)NN * CD * 4);
    float* xl2     = (float*)carve((size_t)NN * C2 * 4);
    float* hl2     = (float*)carve((size_t)NM * C2 * 4);
    float* sn2     = (float*)carve((size_t)NN * 4);
    float* sh2     = (float*)carve((size_t)NM * 4);
    float* alpha2  = (float*)carve((size_t)NE * 4);
    float* edge_out2=(float*)carve((size_t)NM * C2 * 4);

    // zero degree + fill counters
    hipMemsetAsync(d_ws, 0, (size_t)(zero_end - (char*)d_ws), stream);

    // CSR build
    count_deg_kernel<<<CDIV(NE, 256), 256, 0, stream>>>(node_idx, hedge_idx, deg_node, deg_hedge);
    scan_kernel<<<1, 1024, 0, stream>>>(deg_node, node_off, NN);
    scan_kernel<<<1, 1024, 0, stream>>>(deg_hedge, hedge_off, NM);
    fill_kernel<<<CDIV(NE, 256), 256, 0, stream>>>(node_idx, hedge_idx, node_off, hedge_off,
                                                   cnt_node, cnt_hedge, node_inc, hedge_inc);

    // ---- conv1 ----
    hedge_sum_kernel<<<NM, 256, 0, stream>>>(x, node_idx, hedge_inc, hedge_off, h_attr);
    gemm256_kernel<<<dim3(CDIV(NN, 64), 4), 256, 0, stream>>>(x, W1, xl, NN);
    gemm256_kernel<<<dim3(CDIV(NM, 64), 4), 256, 0, stream>>>(h_attr, W1, hl, NM);
    scores8_kernel<<<NN, 256, 0, stream>>>(xl, att1, 0, sn, NN);
    scores8_kernel<<<NM, 256, 0, stream>>>(hl, att1, 32, sh, NM);
    hedge_attn1_kernel<<<NM, 256, 0, stream>>>(xl, sn, sh, node_idx, hedge_inc, hedge_off,
                                               alphaE, edge_out);
    node_agg1_kernel<<<NN, 256, 0, stream>>>(edge_out, alphaE, hedge_idx, node_inc, node_off,
                                             b1, hbuf);

    // ---- conv2 ----
    hedge_sum_kernel<<<NM, 256, 0, stream>>>(hbuf, node_idx, hedge_inc, hedge_off, h_attr);
    gemm16_kernel<<<CDIV(NN, 16), 256, 0, stream>>>(hbuf, W2, xl2, NN);
    gemm16_kernel<<<CDIV(NM, 16), 256, 0, stream>>>(h_attr, W2, hl2, NM);
    scores1_kernel<<<CDIV(NN, 16), 256, 0, stream>>>(xl2, att2, 0, sn2, NN);
    scores1_kernel<<<CDIV(NM, 16), 256, 0, stream>>>(hl2, att2, 16, sh2, NM);
    hedge_attn2_kernel<<<NM, 256, 0, stream>>>(xl2, sn2, sh2, node_idx, hedge_inc, hedge_off,
                                               alpha2, edge_out2);
    node_out2_kernel<<<NN, 64, 0, stream>>>(edge_out2, alpha2, hedge_idx, node_inc, node_off,
                                            b2, out);
}

// Round 2
// 533.141 us; speedup vs baseline: 1.8096x; 1.8096x over previous
//
#include <hip/hip_runtime.h>
#include <hip/hip_bf16.h>
#include <math.h>

#define NN 50000
#define NM 10000
#define NE 400000
#define CD 256
#define C2 16
#define CACHE1 88

#define CDIV(a,b) (((a)+(b)-1)/(b))

typedef __attribute__((ext_vector_type(8))) short short8v;
typedef __attribute__((ext_vector_type(8))) unsigned short ushort8v;
typedef __attribute__((ext_vector_type(4))) float f32x4;

__device__ __forceinline__ float bflo(unsigned int u) { return __uint_as_float(u << 16); }
__device__ __forceinline__ float bfhi(unsigned int u) { return __uint_as_float(u & 0xffff0000u); }
__device__ __forceinline__ unsigned short f2bf(float f) {
    union { __hip_bfloat16 h; unsigned short u; } cv;
    cv.h = __float2bfloat16(f);
    return cv.u;
}
__device__ __forceinline__ unsigned int packbf2(float a, float b) {
    return (unsigned int)f2bf(a) | ((unsigned int)f2bf(b) << 16);
}
__device__ __forceinline__ float bf1(unsigned short u) { return __uint_as_float(((unsigned int)u) << 16); }

// ---------------- CSR build ----------------

__global__ void count_deg_kernel(const int* __restrict__ node_idx, const int* __restrict__ hedge_idx,
                                 int* __restrict__ deg_node, int* __restrict__ deg_hedge) {
    int e = blockIdx.x * 256 + threadIdx.x;
    if (e < NE) {
        atomicAdd(&deg_node[node_idx[e]], 1);
        atomicAdd(&deg_hedge[hedge_idx[e]], 1);
    }
}

__global__ __launch_bounds__(1024) void scan1_kernel(const int* __restrict__ deg, int* __restrict__ off,
                                                     int* __restrict__ bsum, int n) {
    __shared__ int lds[1024];
    int t = threadIdx.x, b = blockIdx.x;
    int i = b * 1024 + t;
    int v = (i < n) ? deg[i] : 0;
    lds[t] = v;
    __syncthreads();
    for (int s = 1; s < 1024; s <<= 1) {
        int tv = (t >= s) ? lds[t - s] : 0;
        __syncthreads();
        lds[t] += tv;
        __syncthreads();
    }
    if (i < n) off[i] = lds[t] - v;
    if (t == 1023) bsum[b] = lds[t];
}

__global__ void scan2_kernel(int* __restrict__ bsum, int nb, int* __restrict__ off_last) {
    __shared__ int s[64];
    int t = threadIdx.x;
    if (t < nb) s[t] = bsum[t];
    __syncthreads();
    if (t == 0) {
        int run = 0;
        for (int j = 0; j < nb; ++j) { int tmp = s[j]; s[j] = run; run += tmp; }
        *off_last = run;
    }
    __syncthreads();
    if (t < nb) bsum[t] = s[t];
}

__global__ __launch_bounds__(1024) void scan3_kernel(int* __restrict__ off, const int* __restrict__ bsum, int n) {
    int i = blockIdx.x * 1024 + threadIdx.x;
    if (i < n) off[i] += bsum[blockIdx.x];
}

// fill: build node-CSR (mcol = hedge of each node-slot) and hedge-CSR (ncol = node of each
// hedge-slot, pnh = node-CSR position of each hedge-slot, for alpha scatter)
__global__ void fill_kernel(const int* __restrict__ node_idx, const int* __restrict__ hedge_idx,
                            const int* __restrict__ node_off, const int* __restrict__ hedge_off,
                            int* __restrict__ cnt_node, int* __restrict__ cnt_hedge,
                            int* __restrict__ mcol, int* __restrict__ ncol, int* __restrict__ pnh) {
    int e = blockIdx.x * 256 + threadIdx.x;
    if (e < NE) {
        int n = node_idx[e];
        int m = hedge_idx[e];
        int p = node_off[n] + atomicAdd(&cnt_node[n], 1);
        int q = hedge_off[m] + atomicAdd(&cnt_hedge[m], 1);
        mcol[p] = m;
        ncol[q] = n;
        pnh[q] = p;
    }
}

// ---------------- W1 -> bf16 transposed [col][k] ----------------
__global__ void convW1_kernel(const float* __restrict__ W1, unsigned short* __restrict__ W1t) {
    int n = blockIdx.x, k = threadIdx.x;
    W1t[n * 256 + k] = f2bf(W1[k * 256 + n]);
}

// ---------------- MFMA GEMM: xl(bf16)[R,256] = A(f32)[R,256] @ W1; fused node scores sn ----------------
__global__ __launch_bounds__(256) void gemm256_mfma(const float* __restrict__ A,
        const unsigned short* __restrict__ Bt, const float* __restrict__ att1,
        unsigned short* __restrict__ Cbf, float* __restrict__ sn, int R) {
    __shared__ unsigned short As[64 * 40];
    __shared__ unsigned short Bs[64 * 40];
    __shared__ float Cs[64 * 65];
    __shared__ float red[256];
    int t = threadIdx.x;
    int row0 = blockIdx.x * 64;
    int col0 = blockIdx.y * 64;
    int lane = t & 63, wave = t >> 6;
    int wrow = (wave >> 1) * 32, wcol = (wave & 1) * 32;
    int quad = lane >> 4, l15 = lane & 15;
    f32x4 acc[2][2] = {};
    for (int k0 = 0; k0 < 256; k0 += 32) {
        #pragma unroll
        for (int p = 0; p < 2; ++p) {
            int li = t + p * 256;
            int r = li >> 3, kq = li & 7;
            float4 x4 = make_float4(0.f, 0.f, 0.f, 0.f);
            if (row0 + r < R) x4 = *(const float4*)&A[(size_t)(row0 + r) * 256 + k0 + kq * 4];
            ushort4 u;
            u.x = f2bf(x4.x); u.y = f2bf(x4.y); u.z = f2bf(x4.z); u.w = f2bf(x4.w);
            *(ushort4*)&As[r * 40 + kq * 4] = u;
        }
        {
            int c = t >> 2, q = t & 3;
            *(ushort8v*)&Bs[c * 40 + q * 8] = *(const ushort8v*)&Bt[(size_t)(col0 + c) * 256 + k0 + q * 8];
        }
        __syncthreads();
        short8v a[2], b[2];
        #pragma unroll
        for (int mi = 0; mi < 2; ++mi)
            a[mi] = *(const short8v*)&As[(wrow + mi * 16 + l15) * 40 + quad * 8];
        #pragma unroll
        for (int ni = 0; ni < 2; ++ni)
            b[ni] = *(const short8v*)&Bs[(wcol + ni * 16 + l15) * 40 + quad * 8];
        #pragma unroll
        for (int mi = 0; mi < 2; ++mi)
            #pragma unroll
            for (int ni = 0; ni < 2; ++ni)
                acc[mi][ni] = __builtin_amdgcn_mfma_f32_16x16x32_bf16(a[mi], b[ni], acc[mi][ni], 0, 0, 0);
        __syncthreads();
    }
    #pragma unroll
    for (int mi = 0; mi < 2; ++mi)
        #pragma unroll
        for (int ni = 0; ni < 2; ++ni)
            #pragma unroll
            for (int rg = 0; rg < 4; ++rg) {
                int rr = wrow + mi * 16 + quad * 4 + rg;
                int cc = wcol + ni * 16 + l15;
                Cs[rr * 65 + cc] = acc[mi][ni][rg];
            }
    __syncthreads();
    // fused scores: this 64-col block covers heads h0, h0+1 fully (node half of att1)
    {
        int r = t & 63, hh = t >> 6;
        int hh01 = hh & 1, kh = hh >> 1;
        int h0 = col0 >> 5;
        float psum = 0.f;
        #pragma unroll
        for (int j = 0; j < 16; ++j)
            psum += Cs[r * 65 + hh01 * 32 + kh * 16 + j] * att1[(h0 + hh01) * 64 + kh * 16 + j];
        red[t] = psum;
        __syncthreads();
        if (t < 128) {
            float tot = red[t] + red[t + 128];
            int rr = t & 63, hx = t >> 6;
            if (row0 + rr < R) sn[(size_t)(row0 + rr) * 8 + h0 + hx] = tot;
        }
    }
    // bf16 pack + write
    {
        int r = t >> 2, c0q = (t & 3) * 16;
        if (row0 + r < R) {
            unsigned short tmp[16];
            #pragma unroll
            for (int j = 0; j < 16; ++j) tmp[j] = f2bf(Cs[r * 65 + c0q + j]);
            *(ushort8v*)&Cbf[(size_t)(row0 + r) * 256 + col0 + c0q] = *(ushort8v*)&tmp[0];
            *(ushort8v*)&Cbf[(size_t)(row0 + r) * 256 + col0 + c0q + 8] = *(ushort8v*)&tmp[8];
        }
    }
}

// ---------------- conv1 fused per-hedge: hl-sum -> sh -> softmax -> alpha + edge_out ----------------
__global__ __launch_bounds__(256) void hedge_fused1(const unsigned short* __restrict__ xl,
        const float* __restrict__ sn, const float* __restrict__ att1,
        const int* __restrict__ ncol, const int* __restrict__ pnh, const int* __restrict__ offs,
        float* __restrict__ alpha_csr, unsigned short* __restrict__ edge_out) {
    __shared__ int nl[1024];
    __shared__ unsigned int cache[CACHE1][128];
    __shared__ float shA[256], shB[256];
    __shared__ float red[256];
    __shared__ float shv[8], mhv[8], invv[8];
    int m = blockIdx.x;
    int beg = offs[m], d = offs[m + 1] - beg;
    int t = threadIdx.x;
    for (int i = t; i < d; i += 256) nl[i] = ncol[beg + i];
    __syncthreads();
    int rs = t >> 7, c2 = t & 127;
    // pass A: sum xl rows (for sh), cache rows in LDS
    float s0 = 0.f, s1 = 0.f;
    for (int i = rs; i < d; i += 2) {
        unsigned int u = *(const unsigned int*)&xl[(size_t)nl[i] * 256 + c2 * 2];
        if (i < CACHE1) cache[i][c2] = u;
        s0 += bflo(u); s1 += bfhi(u);
    }
    shA[t] = s0; shB[t] = s1;
    __syncthreads();
    if (t < 128) {
        float ch0 = shA[t] + shA[t + 128];
        float ch1 = shB[t] + shB[t + 128];
        int c0 = 2 * t, c1 = 2 * t + 1;
        float v = ch0 * att1[(c0 >> 5) * 64 + 32 + (c0 & 31)]
                + ch1 * att1[(c1 >> 5) * 64 + 32 + (c1 & 31)];
        #pragma unroll
        for (int s = 8; s; s >>= 1) v += __shfl_xor(v, s);
        if ((t & 15) == 0) shv[t >> 4] = v;
    }
    __syncthreads();
    int h = t & 7, sl = t >> 3;
    float shvh = shv[h];
    // per-head max
    float pm = -1e30f;
    for (int i = sl; i < d; i += 32) {
        float s = sn[(size_t)nl[i] * 8 + h] + shvh;
        s = s > 0.f ? s : 0.2f * s;
        pm = fmaxf(pm, s);
    }
    red[t] = pm; __syncthreads();
    for (int s2 = 16; s2; s2 >>= 1) { if (sl < s2) red[t] = fmaxf(red[t], red[t + s2 * 8]); __syncthreads(); }
    if (t < 8) mhv[t] = red[t];
    __syncthreads();
    float mh = mhv[h];
    // sum of exp
    float ps = 0.f;
    for (int i = sl; i < d; i += 32) {
        float s = sn[(size_t)nl[i] * 8 + h] + shvh;
        s = s > 0.f ? s : 0.2f * s;
        ps += __expf(s - mh);
    }
    red[t] = ps; __syncthreads();
    for (int s2 = 16; s2; s2 >>= 1) { if (sl < s2) red[t] += red[t + s2 * 8]; __syncthreads(); }
    if (t < 8) invv[t] = 1.0f / (red[t] + 1e-16f);
    __syncthreads();
    float iv = invv[h];
    // alpha scatter (node-CSR order)
    for (int i = sl; i < d; i += 32) {
        float s = sn[(size_t)nl[i] * 8 + h] + shvh;
        s = s > 0.f ? s : 0.2f * s;
        alpha_csr[(size_t)pnh[beg + i] * 8 + h] = __expf(s - mh) * iv;
    }
    // pass B: weighted sum -> edge_out (bf16)
    int hh = c2 >> 4;
    float mh2 = mhv[hh], iv2 = invv[hh], sv2 = shv[hh];
    float a0 = 0.f, a1 = 0.f;
    for (int i = rs; i < d; i += 2) {
        float s = sn[(size_t)nl[i] * 8 + hh] + sv2;
        s = s > 0.f ? s : 0.2f * s;
        float a = __expf(s - mh2) * iv2;
        unsigned int u = (i < CACHE1) ? cache[i][c2]
                                      : *(const unsigned int*)&xl[(size_t)nl[i] * 256 + c2 * 2];
        a0 += a * bflo(u); a1 += a * bfhi(u);
    }
    __syncthreads();
    shA[t] = a0; shB[t] = a1;
    __syncthreads();
    if (t < 128) {
        float Bv = d ? 1.0f / (float)d : 0.0f;
        float c0 = (shA[t] + shA[t + 128]) * Bv;
        float c1 = (shB[t] + shB[t + 128]) * Bv;
        ((unsigned int*)edge_out)[(size_t)m * 128 + t] = packbf2(c0, c1);
    }
}

// ---------------- conv1 node aggregation: 2 nodes/block, bf16 pair lanes ----------------
__global__ __launch_bounds__(256) void node_agg1b(const unsigned short* __restrict__ edge_out,
        const float* __restrict__ alpha_csr, const int* __restrict__ mcol,
        const int* __restrict__ offs, const float* __restrict__ b1, unsigned short* __restrict__ hbuf) {
    int t = threadIdx.x;
    int slot = t >> 7, c2 = t & 127;
    int n = blockIdx.x * 2 + slot;
    int beg = offs[n], end = offs[n + 1];
    int hh = c2 >> 4;
    float a0 = 0.f, a1 = 0.f;
    for (int p = beg; p < end; ++p) {
        float a = alpha_csr[(size_t)p * 8 + hh];
        unsigned int u = ((const unsigned int*)edge_out)[(size_t)mcol[p] * 128 + c2];
        a0 += a * bflo(u); a1 += a * bfhi(u);
    }
    int dd = end - beg;
    float D = dd ? 1.0f / (float)dd : 0.0f;
    float v0 = a0 * D + b1[c2 * 2];
    float v1 = a1 * D + b1[c2 * 2 + 1];
    v0 = v0 > 0.f ? v0 : 0.f;
    v1 = v1 > 0.f ? v1 : 0.f;
    ((unsigned int*)hbuf)[(size_t)n * 128 + c2] = packbf2(v0, v1);
}

// ---------------- conv2 GEMM: xl2[R,16] = h(bf16)[R,256] @ W2; fused sn2 ----------------
__global__ __launch_bounds__(256) void gemm16f(const unsigned short* __restrict__ A,
        const float* __restrict__ W2, const float* __restrict__ att2,
        float* __restrict__ xl2, float* __restrict__ sn2, int R) {
    __shared__ float W2L[256 * 16];
    __shared__ unsigned short AL[16 * 256];
    int t = threadIdx.x;
    int r0 = blockIdx.x * 16;
    for (int i = t; i < 4096; i += 256) W2L[i] = W2[i];
    for (int i = t; i < 1024; i += 256) {
        int r = i >> 6, q = i & 63;
        ushort4 u;
        if (r0 + r < R) u = *(const ushort4*)&A[(size_t)(r0 + r) * 256 + q * 4];
        else { u.x = 0; u.y = 0; u.z = 0; u.w = 0; }
        ((ushort4*)AL)[i] = u;
    }
    __syncthreads();
    int r = t >> 4, c = t & 15;
    float acc = 0.f;
    for (int k = 0; k < 256; k += 4) {
        ushort4 av = *(const ushort4*)&AL[r * 256 + k];
        acc += bf1(av.x) * W2L[k * 16 + c] + bf1(av.y) * W2L[(k + 1) * 16 + c]
             + bf1(av.z) * W2L[(k + 2) * 16 + c] + bf1(av.w) * W2L[(k + 3) * 16 + c];
    }
    float sv = acc * att2[c];
    #pragma unroll
    for (int s = 8; s; s >>= 1) sv += __shfl_xor(sv, s);
    int gr = r0 + r;
    if (gr < R) {
        xl2[(size_t)gr * 16 + c] = acc;
        if (c == 0) sn2[gr] = sv;
    }
}

// ---------------- conv2 fused per-hedge ----------------
__global__ __launch_bounds__(256) void hedge_fused2(const float* __restrict__ xl2,
        const float* __restrict__ sn2, const float* __restrict__ att2,
        const int* __restrict__ ncol, const int* __restrict__ pnh, const int* __restrict__ offs,
        float* __restrict__ alpha2, float* __restrict__ edge_out2) {
    __shared__ int nl[1024];
    __shared__ float xc[256 * 16];
    __shared__ float red[256];
    __shared__ float sh_s, mh_s, inv_s;
    int m = blockIdx.x;
    int beg = offs[m], d = offs[m + 1] - beg;
    int t = threadIdx.x;
    for (int i = t; i < d; i += 256) nl[i] = ncol[beg + i];
    __syncthreads();
    int ip = t >> 4, c = t & 15;
    float hs = 0.f;
    for (int i = ip; i < d; i += 16) {
        float v = xl2[(size_t)nl[i] * 16 + c];
        if (i < 256) xc[i * 16 + c] = v;
        hs += v;
    }
    red[t] = hs; __syncthreads();
    for (int s2 = 8; s2; s2 >>= 1) { if (ip < s2) red[t] += red[t + s2 * 16]; __syncthreads(); }
    if (t < 16) {
        float v = red[t] * att2[16 + t];
        #pragma unroll
        for (int s = 8; s; s >>= 1) v += __shfl_xor(v, s);
        if (t == 0) sh_s = v;
    }
    __syncthreads();
    float shv = sh_s;
    float pm = -1e30f;
    for (int i = t; i < d; i += 256) {
        float s = sn2[nl[i]] + shv; s = s > 0.f ? s : 0.2f * s;
        pm = fmaxf(pm, s);
    }
    red[t] = pm; __syncthreads();
    for (int s2 = 128; s2; s2 >>= 1) { if (t < s2) red[t] = fmaxf(red[t], red[t + s2]); __syncthreads(); }
    if (t == 0) mh_s = red[0];
    __syncthreads();
    float mh = mh_s;
    float ps = 0.f;
    for (int i = t; i < d; i += 256) {
        float s = sn2[nl[i]] + shv; s = s > 0.f ? s : 0.2f * s;
        ps += __expf(s - mh);
    }
    red[t] = ps; __syncthreads();
    for (int s2 = 128; s2; s2 >>= 1) { if (t < s2) red[t] += red[t + s2]; __syncthreads(); }
    if (t == 0) inv_s = 1.0f / (red[0] + 1e-16f);
    __syncthreads();
    float inv = inv_s;
    for (int i = t; i < d; i += 256) {
        float s = sn2[nl[i]] + shv; s = s > 0.f ? s : 0.2f * s;
        alpha2[pnh[beg + i]] = __expf(s - mh) * inv;
    }
    float acc = 0.f;
    for (int i = ip; i < d; i += 16) {
        float s = sn2[nl[i]] + shv; s = s > 0.f ? s : 0.2f * s;
        float a = __expf(s - mh) * inv;
        float v = (i < 256) ? xc[i * 16 + c] : xl2[(size_t)nl[i] * 16 + c];
        acc += a * v;
    }
    __syncthreads();
    red[t] = acc; __syncthreads();
    for (int s2 = 8; s2; s2 >>= 1) { if (ip < s2) red[t] += red[t + s2 * 16]; __syncthreads(); }
    if (t < 16) {
        float Bv = d ? 1.0f / (float)d : 0.0f;
        edge_out2[(size_t)m * 16 + t] = red[t] * Bv;
    }
}

// ---------------- conv2 node aggregation + log_softmax: 16 nodes/block ----------------
__global__ __launch_bounds__(256) void node_out2b(const float* __restrict__ edge_out2,
        const float* __restrict__ alpha2, const int* __restrict__ mcol,
        const int* __restrict__ offs, const float* __restrict__ b2, float* __restrict__ out) {
    int t = threadIdx.x;
    int n = blockIdx.x * 16 + (t >> 4);
    int c = t & 15;
    int beg = offs[n], end = offs[n + 1];
    float acc = 0.f;
    for (int p = beg; p < end; ++p)
        acc += alpha2[p] * edge_out2[(size_t)mcol[p] * 16 + c];
    int dd = end - beg;
    float D = dd ? 1.0f / (float)dd : 0.0f;
    float v = acc * D + b2[c];
    float mx = v;
    #pragma unroll
    for (int s = 8; s; s >>= 1) mx = fmaxf(mx, __shfl_xor(mx, s));
    float ex = __expf(v - mx);
    float sm = ex;
    #pragma unroll
    for (int s = 8; s; s >>= 1) sm += __shfl_xor(sm, s);
    out[(size_t)n * 16 + c] = (v - mx) - logf(sm);
}

extern "C" void kernel_launch(void* const* d_in, const int* in_sizes, int n_in,
                              void* d_out, int out_size, void* d_ws, size_t ws_size,
                              hipStream_t stream) {
    const float* x        = (const float*)d_in[0];
    const int*   node_idx = (const int*)d_in[1];
    const int*   hedge_idx= (const int*)d_in[2];
    const float* W1       = (const float*)d_in[3];
    const float* att1     = (const float*)d_in[4];
    const float* b1       = (const float*)d_in[5];
    const float* W2       = (const float*)d_in[6];
    const float* att2     = (const float*)d_in[7];
    const float* b2       = (const float*)d_in[8];
    float* out = (float*)d_out;

    char* w = (char*)d_ws;
    auto carve = [&](size_t bytes) -> char* {
        char* p = w;
        w += (bytes + 255) & ~(size_t)255;
        return p;
    };
    int* deg_node  = (int*)carve((size_t)NN * 4);
    int* deg_hedge = (int*)carve((size_t)NM * 4);
    int* cnt_node  = (int*)carve((size_t)NN * 4);
    int* cnt_hedge = (int*)carve((size_t)NM * 4);
    char* zero_end = w;
    int* node_off  = (int*)carve((size_t)(NN + 1) * 4);
    int* hedge_off = (int*)carve((size_t)(NM + 1) * 4);
    int* bsum_n    = (int*)carve(64 * 4);
    int* bsum_h    = (int*)carve(64 * 4);
    int* mcol      = (int*)carve((size_t)NE * 4);
    int* ncol      = (int*)carve((size_t)NE * 4);
    int* pnh       = (int*)carve((size_t)NE * 4);
    unsigned short* W1t = (unsigned short*)carve((size_t)256 * 256 * 2);
    unsigned short* xl  = (unsigned short*)carve((size_t)NN * CD * 2);
    float* sn      = (float*)carve((size_t)NN * 8 * 4);
    float* alpha_csr = (float*)carve((size_t)NE * 8 * 4);
    unsigned short* edge_out = (unsigned short*)carve((size_t)NM * CD * 2);
    unsigned short* hbuf     = (unsigned short*)carve((size_t)NN * CD * 2);
    float* xl2     = (float*)carve((size_t)NN * C2 * 4);
    float* sn2     = (float*)carve((size_t)NN * 4);
    float* alpha2  = (float*)carve((size_t)NE * 4);
    float* edge_out2 = (float*)carve((size_t)NM * C2 * 4);

    hipMemsetAsync(d_ws, 0, (size_t)(zero_end - (char*)d_ws), stream);

    convW1_kernel<<<256, 256, 0, stream>>>(W1, W1t);
    count_deg_kernel<<<CDIV(NE, 256), 256, 0, stream>>>(node_idx, hedge_idx, deg_node, deg_hedge);

    int nbN = CDIV(NN, 1024), nbM = CDIV(NM, 1024);
    scan1_kernel<<<nbN, 1024, 0, stream>>>(deg_node, node_off, bsum_n, NN);
    scan2_kernel<<<1, 64, 0, stream>>>(bsum_n, nbN, node_off + NN);
    scan3_kernel<<<nbN, 1024, 0, stream>>>(node_off, bsum_n, NN);
    scan1_kernel<<<nbM, 1024, 0, stream>>>(deg_hedge, hedge_off, bsum_h, NM);
    scan2_kernel<<<1, 64, 0, stream>>>(bsum_h, nbM, hedge_off + NM);
    scan3_kernel<<<nbM, 1024, 0, stream>>>(hedge_off, bsum_h, NM);

    fill_kernel<<<CDIV(NE, 256), 256, 0, stream>>>(node_idx, hedge_idx, node_off, hedge_off,
                                                   cnt_node, cnt_hedge, mcol, ncol, pnh);

    // ---- conv1 ----
    gemm256_mfma<<<dim3(CDIV(NN, 64), 4), 256, 0, stream>>>(x, W1t, att1, xl, sn, NN);
    hedge_fused1<<<NM, 256, 0, stream>>>(xl, sn, att1, ncol, pnh, hedge_off, alpha_csr, edge_out);
    node_agg1b<<<NN / 2, 256, 0, stream>>>(edge_out, alpha_csr, mcol, node_off, b1, hbuf);

    // ---- conv2 ----
    gemm16f<<<CDIV(NN, 16), 256, 0, stream>>>(hbuf, W2, att2, xl2, sn2, NN);
    hedge_fused2<<<NM, 256, 0, stream>>>(xl2, sn2, att2, ncol, pnh, hedge_off, alpha2, edge_out2);
    node_out2b<<<CDIV(NN, 16), 256, 0, stream>>>(edge_out2, alpha2, mcol, node_off, b2, out);
}

// Round 3
// 371.050 us; speedup vs baseline: 2.6001x; 1.4368x over previous
//
#include <hip/hip_runtime.h>
#include <hip/hip_bf16.h>
#include <math.h>

#define NN 50000
#define NM 10000
#define NE 400000
#define CD 256
#define C2 16

#define CDIV(a,b) (((a)+(b)-1)/(b))

typedef __attribute__((ext_vector_type(8))) short short8v;
typedef __attribute__((ext_vector_type(8))) unsigned short ushort8v;
typedef __attribute__((ext_vector_type(4))) float f32x4;

__device__ __forceinline__ float bflo(unsigned int u) { return __uint_as_float(u << 16); }
__device__ __forceinline__ float bfhi(unsigned int u) { return __uint_as_float(u & 0xffff0000u); }
__device__ __forceinline__ unsigned short f2bf(float f) {
    union { __hip_bfloat16 h; unsigned short u; } cv;
    cv.h = __float2bfloat16(f);
    return cv.u;
}
__device__ __forceinline__ unsigned int packbf2(float a, float b) {
    return (unsigned int)f2bf(a) | ((unsigned int)f2bf(b) << 16);
}
__device__ __forceinline__ float bf1(unsigned short u) { return __uint_as_float(((unsigned int)u) << 16); }
__device__ __forceinline__ float lrelu(float s) { return s > 0.f ? s : 0.2f * s; }

// ---------------- CSR build ----------------

__global__ void count_deg_kernel(const int* __restrict__ node_idx, const int* __restrict__ hedge_idx,
                                 int* __restrict__ deg_node, int* __restrict__ deg_hedge) {
    int e = blockIdx.x * 256 + threadIdx.x;
    if (e < NE) {
        atomicAdd(&deg_node[node_idx[e]], 1);
        atomicAdd(&deg_hedge[hedge_idx[e]], 1);
    }
}

__global__ __launch_bounds__(1024) void scan1_kernel(const int* __restrict__ deg, int* __restrict__ off,
                                                     int* __restrict__ bsum, int n) {
    __shared__ int lds[1024];
    int t = threadIdx.x, b = blockIdx.x;
    int i = b * 1024 + t;
    int v = (i < n) ? deg[i] : 0;
    lds[t] = v;
    __syncthreads();
    for (int s = 1; s < 1024; s <<= 1) {
        int tv = (t >= s) ? lds[t - s] : 0;
        __syncthreads();
        lds[t] += tv;
        __syncthreads();
    }
    if (i < n) off[i] = lds[t] - v;
    if (t == 1023) bsum[b] = lds[t];
}

__global__ void scan2_kernel(int* __restrict__ bsum, int nb, int* __restrict__ off_last) {
    __shared__ int s[64];
    int t = threadIdx.x;
    if (t < nb) s[t] = bsum[t];
    __syncthreads();
    if (t == 0) {
        int run = 0;
        for (int j = 0; j < nb; ++j) { int tmp = s[j]; s[j] = run; run += tmp; }
        *off_last = run;
    }
    __syncthreads();
    if (t < nb) bsum[t] = s[t];
}

__global__ __launch_bounds__(1024) void scan3_kernel(int* __restrict__ off, const int* __restrict__ bsum, int n) {
    int i = blockIdx.x * 1024 + threadIdx.x;
    if (i < n) off[i] += bsum[blockIdx.x];
}

__global__ void fill_kernel(const int* __restrict__ node_idx, const int* __restrict__ hedge_idx,
                            const int* __restrict__ node_off, const int* __restrict__ hedge_off,
                            int* __restrict__ cnt_node, int* __restrict__ cnt_hedge,
                            int* __restrict__ mcol, int* __restrict__ ncol, int* __restrict__ pnh) {
    int e = blockIdx.x * 256 + threadIdx.x;
    if (e < NE) {
        int n = node_idx[e];
        int m = hedge_idx[e];
        int p = node_off[n] + atomicAdd(&cnt_node[n], 1);
        int q = hedge_off[m] + atomicAdd(&cnt_hedge[m], 1);
        mcol[p] = m;
        ncol[q] = n;
        pnh[q] = p;
    }
}

// ---------------- W1 -> bf16 transposed [col][k] ----------------
__global__ void convW1_kernel(const float* __restrict__ W1, unsigned short* __restrict__ W1t) {
    int n = blockIdx.x, k = threadIdx.x;
    W1t[n * 256 + k] = f2bf(W1[k * 256 + n]);
}

// ---------------- MFMA GEMM: xl(bf16)[R,256] = A(f32)[R,256] @ W1; fused sn+snh into sns[R,16] ----------------
// tile 64 rows x 256 cols, 4 waves; LDS aliased: staging (25.6KB) then C col-halves (33KB)
__global__ __launch_bounds__(256) void gemm256_mfma(const float* __restrict__ A,
        const unsigned short* __restrict__ Bt, const float* __restrict__ att1,
        unsigned short* __restrict__ Cbf, float* __restrict__ sns, int R) {
    __shared__ float smem[8512];                             // 34 KB
    unsigned short* As = (unsigned short*)smem;              // [64][40]
    unsigned short* Bs = (unsigned short*)(smem + 1280);     // [256][40]
    int t = threadIdx.x;
    int row0 = blockIdx.x * 64;
    int lane = t & 63, wave = t >> 6;
    int wrow = (wave >> 1) * 32, wcol = (wave & 1) * 128;
    int quad = lane >> 4, l15 = lane & 15;
    f32x4 acc[2][8] = {};
    for (int k0 = 0; k0 < 256; k0 += 32) {
        #pragma unroll
        for (int p = 0; p < 2; ++p) {
            int li = t + p * 256;
            int r = li >> 3, kq = li & 7;
            float4 x4 = make_float4(0.f, 0.f, 0.f, 0.f);
            if (row0 + r < R) x4 = *(const float4*)&A[(size_t)(row0 + r) * 256 + k0 + kq * 4];
            ushort4 u;
            u.x = f2bf(x4.x); u.y = f2bf(x4.y); u.z = f2bf(x4.z); u.w = f2bf(x4.w);
            *(ushort4*)&As[r * 40 + kq * 4] = u;
        }
        #pragma unroll
        for (int p = 0; p < 4; ++p) {
            int li = t + p * 256;
            int c = li >> 2, q = li & 3;
            *(ushort8v*)&Bs[c * 40 + q * 8] = *(const ushort8v*)&Bt[(size_t)c * 256 + k0 + q * 8];
        }
        __syncthreads();
        short8v a[2], b[8];
        #pragma unroll
        for (int mi = 0; mi < 2; ++mi)
            a[mi] = *(const short8v*)&As[(wrow + mi * 16 + l15) * 40 + quad * 8];
        #pragma unroll
        for (int ni = 0; ni < 8; ++ni)
            b[ni] = *(const short8v*)&Bs[(wcol + ni * 16 + l15) * 40 + quad * 8];
        #pragma unroll
        for (int mi = 0; mi < 2; ++mi)
            #pragma unroll
            for (int ni = 0; ni < 8; ++ni)
                acc[mi][ni] = __builtin_amdgcn_mfma_f32_16x16x32_bf16(a[mi], b[ni], acc[mi][ni], 0, 0, 0);
        __syncthreads();
    }
    // epilogue: two column halves of 128, C staged through aliased LDS [64][133]
    for (int half = 0; half < 2; ++half) {
        if ((wave & 1) == half) {
            #pragma unroll
            for (int mi = 0; mi < 2; ++mi)
                #pragma unroll
                for (int ni = 0; ni < 8; ++ni)
                    #pragma unroll
                    for (int rg = 0; rg < 4; ++rg)
                        smem[(wrow + mi * 16 + quad * 4 + rg) * 133 + ni * 16 + l15] = acc[mi][ni][rg];
        }
        __syncthreads();
        {   // fused scores: thread owns (row r, head hd); 4 heads per half
            int r = t & 63, hd = t >> 6;
            int hgl = half * 4 + hd;
            float psn = 0.f, psh = 0.f;
            #pragma unroll
            for (int j = 0; j < 32; ++j) {
                float cv = smem[r * 133 + hd * 32 + j];
                psn += cv * att1[hgl * 64 + j];
                psh += cv * att1[hgl * 64 + 32 + j];
            }
            if (row0 + r < R) {
                sns[(size_t)(row0 + r) * 16 + hgl] = psn;
                sns[(size_t)(row0 + r) * 16 + 8 + hgl] = psh;
            }
        }
        {   // bf16 pack + write: thread owns 32 cols of one row
            int r2 = t >> 2, c0 = (t & 3) * 32;
            if (row0 + r2 < R) {
                unsigned int buf[16];
                #pragma unroll
                for (int j = 0; j < 16; ++j)
                    buf[j] = packbf2(smem[r2 * 133 + c0 + 2 * j], smem[r2 * 133 + c0 + 2 * j + 1]);
                size_t base = (size_t)(row0 + r2) * 256 + half * 128 + c0;
                *(ushort8v*)&Cbf[base]      = *(ushort8v*)&buf[0];
                *(ushort8v*)&Cbf[base + 8]  = *(ushort8v*)&buf[4];
                *(ushort8v*)&Cbf[base + 16] = *(ushort8v*)&buf[8];
                *(ushort8v*)&Cbf[base + 24] = *(ushort8v*)&buf[12];
            }
        }
        __syncthreads();
    }
}

// ---------------- conv1 fused per-hedge: sh via snh-sum -> softmax -> alpha + edge_out ----------------
__global__ __launch_bounds__(256) void hedge_fused1(const unsigned short* __restrict__ xl,
        const float* __restrict__ sns,
        const int* __restrict__ ncol, const int* __restrict__ pnh, const int* __restrict__ offs,
        float* __restrict__ alpha_csr, unsigned short* __restrict__ edge_out) {
    __shared__ int nl[1024];
    __shared__ float ssc[256 * 8];
    __shared__ float red[256];
    __shared__ float shB[256];
    __shared__ float shv8[8], mh8[8], inv8[8];
    int m = blockIdx.x;
    int beg = offs[m], d = offs[m + 1] - beg;
    int t = threadIdx.x;
    for (int i = t; i < d; i += 256) nl[i] = ncol[beg + i];
    __syncthreads();
    int h = t & 7, sl = t >> 3;
    // sh[h] = sum_i snh[nl[i], h]
    float sv = 0.f;
    for (int i = sl; i < d; i += 32) sv += sns[(size_t)nl[i] * 16 + 8 + h];
    red[t] = sv; __syncthreads();
    for (int s2 = 16; s2; s2 >>= 1) { if (sl < s2) red[t] += red[t + s2 * 8]; __syncthreads(); }
    if (t < 8) shv8[t] = red[t];
    __syncthreads();
    float shvh = shv8[h];
    // scores (store to LDS for i<256) + max
    float pm = -1e30f;
    for (int i = sl; i < d; i += 32) {
        float s = lrelu(sns[(size_t)nl[i] * 16 + h] + shvh);
        if (i < 256) ssc[i * 8 + h] = s;
        pm = fmaxf(pm, s);
    }
    red[t] = pm; __syncthreads();
    for (int s2 = 16; s2; s2 >>= 1) { if (sl < s2) red[t] = fmaxf(red[t], red[t + s2 * 8]); __syncthreads(); }
    if (t < 8) mh8[t] = red[t];
    __syncthreads();
    float mh = mh8[h];
    // sum of exp
    float ps = 0.f;
    for (int i = sl; i < d; i += 32) {
        float s = (i < 256) ? ssc[i * 8 + h] : lrelu(sns[(size_t)nl[i] * 16 + h] + shvh);
        ps += __expf(s - mh);
    }
    red[t] = ps; __syncthreads();
    for (int s2 = 16; s2; s2 >>= 1) { if (sl < s2) red[t] += red[t + s2 * 8]; __syncthreads(); }
    if (t < 8) inv8[t] = 1.0f / (red[t] + 1e-16f);
    __syncthreads();
    float iv = inv8[h];
    // alpha: normalize in LDS + scatter to node-CSR
    for (int i = sl; i < d; i += 32) {
        float s = (i < 256) ? ssc[i * 8 + h] : lrelu(sns[(size_t)nl[i] * 16 + h] + shvh);
        float a = __expf(s - mh) * iv;
        if (i < 256) ssc[i * 8 + h] = a;
        alpha_csr[(size_t)pnh[beg + i] * 8 + h] = a;
    }
    __syncthreads();
    // weighted xl gather -> edge_out (single pass)
    int c2 = t & 127, rs = t >> 7, hh = c2 >> 4;
    float mh2 = mh8[hh], iv2 = inv8[hh], sv2 = shv8[hh];
    float a0 = 0.f, a1 = 0.f;
    for (int i = rs; i < d; i += 2) {
        float a;
        if (i < 256) a = ssc[i * 8 + hh];
        else {
            float s = lrelu(sns[(size_t)nl[i] * 16 + hh] + sv2);
            a = __expf(s - mh2) * iv2;
        }
        unsigned int u = *(const unsigned int*)&xl[(size_t)nl[i] * 256 + c2 * 2];
        a0 += a * bflo(u); a1 += a * bfhi(u);
    }
    red[t] = a0; shB[t] = a1;
    __syncthreads();
    if (t < 128) {
        float Bv = d ? 1.0f / (float)d : 0.0f;
        float c0 = (red[t] + red[t + 128]) * Bv;
        float c1 = (shB[t] + shB[t + 128]) * Bv;
        ((unsigned int*)edge_out)[(size_t)m * 128 + t] = packbf2(c0, c1);
    }
}

// ---------------- conv1 node aggregation: 2 nodes/block ----------------
__global__ __launch_bounds__(256) void node_agg1b(const unsigned short* __restrict__ edge_out,
        const float* __restrict__ alpha_csr, const int* __restrict__ mcol,
        const int* __restrict__ offs, const float* __restrict__ b1, unsigned short* __restrict__ hbuf) {
    int t = threadIdx.x;
    int slot = t >> 7, c2 = t & 127;
    int n = blockIdx.x * 2 + slot;
    int beg = offs[n], end = offs[n + 1];
    int hh = c2 >> 4;
    float a0 = 0.f, a1 = 0.f;
    for (int p = beg; p < end; ++p) {
        float a = alpha_csr[(size_t)p * 8 + hh];
        unsigned int u = ((const unsigned int*)edge_out)[(size_t)mcol[p] * 128 + c2];
        a0 += a * bflo(u); a1 += a * bfhi(u);
    }
    int dd = end - beg;
    float D = dd ? 1.0f / (float)dd : 0.0f;
    float v0 = a0 * D + b1[c2 * 2];
    float v1 = a1 * D + b1[c2 * 2 + 1];
    v0 = v0 > 0.f ? v0 : 0.f;
    v1 = v1 > 0.f ? v1 : 0.f;
    ((unsigned int*)hbuf)[(size_t)n * 128 + c2] = packbf2(v0, v1);
}

// ---------------- conv2 GEMM: xl2[R,16] = h(bf16)[R,256] @ W2; fused sn2+snh2 -> sns2[R] float2 ----------------
__global__ __launch_bounds__(256) void gemm16f(const unsigned short* __restrict__ A,
        const float* __restrict__ W2, const float* __restrict__ att2,
        float* __restrict__ xl2, float2* __restrict__ sns2, int R) {
    __shared__ float W2L[256 * 16];
    __shared__ unsigned short AL[16 * 256];
    int t = threadIdx.x;
    int r0 = blockIdx.x * 16;
    for (int i = t; i < 4096; i += 256) W2L[i] = W2[i];
    for (int i = t; i < 1024; i += 256) {
        int r = i >> 6, q = i & 63;
        ushort4 u;
        if (r0 + r < R) u = *(const ushort4*)&A[(size_t)(r0 + r) * 256 + q * 4];
        else { u.x = 0; u.y = 0; u.z = 0; u.w = 0; }
        ((ushort4*)AL)[i] = u;
    }
    __syncthreads();
    int r = t >> 4, c = t & 15;
    float acc = 0.f;
    for (int k = 0; k < 256; k += 4) {
        ushort4 av = *(const ushort4*)&AL[r * 256 + k];
        acc += bf1(av.x) * W2L[k * 16 + c] + bf1(av.y) * W2L[(k + 1) * 16 + c]
             + bf1(av.z) * W2L[(k + 2) * 16 + c] + bf1(av.w) * W2L[(k + 3) * 16 + c];
    }
    float svn = acc * att2[c];
    float svh = acc * att2[16 + c];
    #pragma unroll
    for (int s = 8; s; s >>= 1) { svn += __shfl_xor(svn, s); svh += __shfl_xor(svh, s); }
    int gr = r0 + r;
    if (gr < R) {
        xl2[(size_t)gr * 16 + c] = acc;
        if (c == 0) sns2[gr] = make_float2(svn, svh);
    }
}

// ---------------- conv2 fused per-hedge ----------------
__global__ __launch_bounds__(256) void hedge_fused2(const float* __restrict__ xl2,
        const float2* __restrict__ sns2,
        const int* __restrict__ ncol, const int* __restrict__ pnh, const int* __restrict__ offs,
        float* __restrict__ alpha2, float* __restrict__ edge_out2) {
    __shared__ int nl[1024];
    __shared__ float ssc[1024];
    __shared__ float red[256];
    __shared__ float sh_s, mh_s, inv_s;
    int m = blockIdx.x;
    int beg = offs[m], d = offs[m + 1] - beg;
    int t = threadIdx.x;
    for (int i = t; i < d; i += 256) nl[i] = ncol[beg + i];
    __syncthreads();
    // single gather of sns2: stash sn part, sum snh part
    float sv = 0.f;
    for (int i = t; i < d; i += 256) {
        float2 v = sns2[nl[i]];
        ssc[i] = v.x;
        sv += v.y;
    }
    red[t] = sv; __syncthreads();
    for (int s2 = 128; s2; s2 >>= 1) { if (t < s2) red[t] += red[t + s2]; __syncthreads(); }
    if (t == 0) sh_s = red[0];
    __syncthreads();
    float sh = sh_s;
    float pm = -1e30f;
    for (int i = t; i < d; i += 256) {
        float s = lrelu(ssc[i] + sh);
        ssc[i] = s;
        pm = fmaxf(pm, s);
    }
    red[t] = pm; __syncthreads();
    for (int s2 = 128; s2; s2 >>= 1) { if (t < s2) red[t] = fmaxf(red[t], red[t + s2]); __syncthreads(); }
    if (t == 0) mh_s = red[0];
    __syncthreads();
    float mh = mh_s;
    float ps = 0.f;
    for (int i = t; i < d; i += 256) ps += __expf(ssc[i] - mh);
    red[t] = ps; __syncthreads();
    for (int s2 = 128; s2; s2 >>= 1) { if (t < s2) red[t] += red[t + s2]; __syncthreads(); }
    if (t == 0) inv_s = 1.0f / (red[0] + 1e-16f);
    __syncthreads();
    float inv = inv_s;
    for (int i = t; i < d; i += 256) {
        float a = __expf(ssc[i] - mh) * inv;
        ssc[i] = a;
        alpha2[pnh[beg + i]] = a;
    }
    __syncthreads();
    int ip = t >> 4, c = t & 15;
    float acc = 0.f;
    for (int i = ip; i < d; i += 16) acc += ssc[i] * xl2[(size_t)nl[i] * 16 + c];
    red[t] = acc; __syncthreads();
    for (int s2 = 8; s2; s2 >>= 1) { if (ip < s2) red[t] += red[t + s2 * 16]; __syncthreads(); }
    if (t < 16) {
        float Bv = d ? 1.0f / (float)d : 0.0f;
        edge_out2[(size_t)m * 16 + t] = red[t] * Bv;
    }
}

// ---------------- conv2 node aggregation + log_softmax: 16 nodes/block ----------------
__global__ __launch_bounds__(256) void node_out2b(const float* __restrict__ edge_out2,
        const float* __restrict__ alpha2, const int* __restrict__ mcol,
        const int* __restrict__ offs, const float* __restrict__ b2, float* __restrict__ out) {
    int t = threadIdx.x;
    int n = blockIdx.x * 16 + (t >> 4);
    int c = t & 15;
    int beg = offs[n], end = offs[n + 1];
    float acc = 0.f;
    for (int p = beg; p < end; ++p)
        acc += alpha2[p] * edge_out2[(size_t)mcol[p] * 16 + c];
    int dd = end - beg;
    float D = dd ? 1.0f / (float)dd : 0.0f;
    float v = acc * D + b2[c];
    float mx = v;
    #pragma unroll
    for (int s = 8; s; s >>= 1) mx = fmaxf(mx, __shfl_xor(mx, s));
    float ex = __expf(v - mx);
    float sm = ex;
    #pragma unroll
    for (int s = 8; s; s >>= 1) sm += __shfl_xor(sm, s);
    out[(size_t)n * 16 + c] = (v - mx) - logf(sm);
}

extern "C" void kernel_launch(void* const* d_in, const int* in_sizes, int n_in,
                              void* d_out, int out_size, void* d_ws, size_t ws_size,
                              hipStream_t stream) {
    const float* x        = (const float*)d_in[0];
    const int*   node_idx = (const int*)d_in[1];
    const int*   hedge_idx= (const int*)d_in[2];
    const float* W1       = (const float*)d_in[3];
    const float* att1     = (const float*)d_in[4];
    const float* b1       = (const float*)d_in[5];
    const float* W2       = (const float*)d_in[6];
    const float* att2     = (const float*)d_in[7];
    const float* b2       = (const float*)d_in[8];
    float* out = (float*)d_out;

    char* w = (char*)d_ws;
    auto carve = [&](size_t bytes) -> char* {
        char* p = w;
        w += (bytes + 255) & ~(size_t)255;
        return p;
    };
    int* deg_node  = (int*)carve((size_t)NN * 4);
    int* deg_hedge = (int*)carve((size_t)NM * 4);
    int* cnt_node  = (int*)carve((size_t)NN * 4);
    int* cnt_hedge = (int*)carve((size_t)NM * 4);
    char* zero_end = w;
    int* node_off  = (int*)carve((size_t)(NN + 1) * 4);
    int* hedge_off = (int*)carve((size_t)(NM + 1) * 4);
    int* bsum_n    = (int*)carve(64 * 4);
    int* bsum_h    = (int*)carve(64 * 4);
    int* mcol      = (int*)carve((size_t)NE * 4);
    int* ncol      = (int*)carve((size_t)NE * 4);
    int* pnh       = (int*)carve((size_t)NE * 4);
    unsigned short* W1t = (unsigned short*)carve((size_t)256 * 256 * 2);
    unsigned short* xl  = (unsigned short*)carve((size_t)NN * CD * 2);
    float* sns     = (float*)carve((size_t)NN * 16 * 4);
    float* alpha_csr = (float*)carve((size_t)NE * 8 * 4);
    unsigned short* edge_out = (unsigned short*)carve((size_t)NM * CD * 2);
    unsigned short* hbuf     = (unsigned short*)carve((size_t)NN * CD * 2);
    float* xl2     = (float*)carve((size_t)NN * C2 * 4);
    float2* sns2   = (float2*)carve((size_t)NN * 8);
    float* alpha2  = (float*)carve((size_t)NE * 4);
    float* edge_out2 = (float*)carve((size_t)NM * C2 * 4);

    hipMemsetAsync(d_ws, 0, (size_t)(zero_end - (char*)d_ws), stream);

    convW1_kernel<<<256, 256, 0, stream>>>(W1, W1t);
    count_deg_kernel<<<CDIV(NE, 256), 256, 0, stream>>>(node_idx, hedge_idx, deg_node, deg_hedge);

    int nbN = CDIV(NN, 1024), nbM = CDIV(NM, 1024);
    scan1_kernel<<<nbN, 1024, 0, stream>>>(deg_node, node_off, bsum_n, NN);
    scan2_kernel<<<1, 64, 0, stream>>>(bsum_n, nbN, node_off + NN);
    scan3_kernel<<<nbN, 1024, 0, stream>>>(node_off, bsum_n, NN);
    scan1_kernel<<<nbM, 1024, 0, stream>>>(deg_hedge, hedge_off, bsum_h, NM);
    scan2_kernel<<<1, 64, 0, stream>>>(bsum_h, nbM, hedge_off + NM);
    scan3_kernel<<<nbM, 1024, 0, stream>>>(hedge_off, bsum_h, NM);

    fill_kernel<<<CDIV(NE, 256), 256, 0, stream>>>(node_idx, hedge_idx, node_off, hedge_off,
                                                   cnt_node, cnt_hedge, mcol, ncol, pnh);

    // ---- conv1 ----
    gemm256_mfma<<<CDIV(NN, 64), 256, 0, stream>>>(x, W1t, att1, xl, sns, NN);
    hedge_fused1<<<NM, 256, 0, stream>>>(xl, sns, ncol, pnh, hedge_off, alpha_csr, edge_out);
    node_agg1b<<<NN / 2, 256, 0, stream>>>(edge_out, alpha_csr, mcol, node_off, b1, hbuf);

    // ---- conv2 ----
    gemm16f<<<CDIV(NN, 16), 256, 0, stream>>>(hbuf, W2, att2, xl2, sns2, NN);
    hedge_fused2<<<NM, 256, 0, stream>>>(xl2, sns2, ncol, pnh, hedge_off, alpha2, edge_out2);
    node_out2b<<<CDIV(NN, 16), 256, 0, stream>>>(edge_out2, alpha2, mcol, node_off, b2, out);
}

// Round 4
// 287.519 us; speedup vs baseline: 3.3554x; 1.2905x over previous
//
#include <hip/hip_runtime.h>
#include <hip/hip_bf16.h>
#include <math.h>

#define NN 50000
#define NM 10000
#define NE 400000
#define CD 256
#define C2 16

#define CDIV(a,b) (((a)+(b)-1)/(b))

typedef __attribute__((ext_vector_type(8))) short short8v;
typedef __attribute__((ext_vector_type(8))) unsigned short ushort8v;
typedef __attribute__((ext_vector_type(4))) float f32x4;

__device__ __forceinline__ float bflo(unsigned int u) { return __uint_as_float(u << 16); }
__device__ __forceinline__ float bfhi(unsigned int u) { return __uint_as_float(u & 0xffff0000u); }
__device__ __forceinline__ unsigned short f2bf(float f) {
    union { __hip_bfloat16 h; unsigned short u; } cv;
    cv.h = __float2bfloat16(f);
    return cv.u;
}
__device__ __forceinline__ unsigned int packbf2(float a, float b) {
    return (unsigned int)f2bf(a) | ((unsigned int)f2bf(b) << 16);
}
__device__ __forceinline__ float bf1(unsigned short u) { return __uint_as_float(((unsigned int)u) << 16); }
__device__ __forceinline__ float lrelu(float s) { return s > 0.f ? s : 0.2f * s; }

// ---------------- CSR build ----------------

__global__ void count_deg_kernel(const int* __restrict__ node_idx, const int* __restrict__ hedge_idx,
                                 int* __restrict__ deg_node, int* __restrict__ deg_hedge) {
    int e = blockIdx.x * 256 + threadIdx.x;
    if (e < NE) {
        atomicAdd(&deg_node[node_idx[e]], 1);
        atomicAdd(&deg_hedge[hedge_idx[e]], 1);
    }
}

__global__ __launch_bounds__(1024) void scan1_kernel(const int* __restrict__ deg, int* __restrict__ off,
                                                     int* __restrict__ bsum, int n) {
    __shared__ int lds[1024];
    int t = threadIdx.x, b = blockIdx.x;
    int i = b * 1024 + t;
    int v = (i < n) ? deg[i] : 0;
    lds[t] = v;
    __syncthreads();
    for (int s = 1; s < 1024; s <<= 1) {
        int tv = (t >= s) ? lds[t - s] : 0;
        __syncthreads();
        lds[t] += tv;
        __syncthreads();
    }
    if (i < n) off[i] = lds[t] - v;
    if (t == 1023) bsum[b] = lds[t];
}

__global__ void scan2_kernel(int* __restrict__ bsum, int nb, int* __restrict__ off_last) {
    __shared__ int s[64];
    int t = threadIdx.x;
    if (t < nb) s[t] = bsum[t];
    __syncthreads();
    if (t == 0) {
        int run = 0;
        for (int j = 0; j < nb; ++j) { int tmp = s[j]; s[j] = run; run += tmp; }
        *off_last = run;
    }
    __syncthreads();
    if (t < nb) bsum[t] = s[t];
}

__global__ __launch_bounds__(1024) void scan3_kernel(int* __restrict__ off, const int* __restrict__ bsum, int n) {
    int i = blockIdx.x * 1024 + threadIdx.x;
    if (i < n) off[i] += bsum[blockIdx.x];
}

__global__ void fill_kernel(const int* __restrict__ node_idx, const int* __restrict__ hedge_idx,
                            const int* __restrict__ node_off, const int* __restrict__ hedge_off,
                            int* __restrict__ cnt_node, int* __restrict__ cnt_hedge,
                            int* __restrict__ mcol, int* __restrict__ ncol, int* __restrict__ pnh) {
    int e = blockIdx.x * 256 + threadIdx.x;
    if (e < NE) {
        int n = node_idx[e];
        int m = hedge_idx[e];
        int p = node_off[n] + atomicAdd(&cnt_node[n], 1);
        int q = hedge_off[m] + atomicAdd(&cnt_hedge[m], 1);
        mcol[p] = m;
        ncol[q] = n;
        pnh[q] = p;
    }
}

// ---------------- W1 -> bf16 transposed [col][k] ----------------
__global__ void convW1_kernel(const float* __restrict__ W1, unsigned short* __restrict__ W1t) {
    int n = blockIdx.x, k = threadIdx.x;
    W1t[n * 256 + k] = f2bf(W1[k * 256 + n]);
}

// ---------------- MFMA GEMM: xl(bf16)[R,256] = A(f32)[R,256] @ W1; fused sn+snh into sns[R,16] ----------------
__global__ __launch_bounds__(256) void gemm256_mfma(const float* __restrict__ A,
        const unsigned short* __restrict__ Bt, const float* __restrict__ att1,
        unsigned short* __restrict__ Cbf, float* __restrict__ sns, int R) {
    __shared__ float smem[8512];                             // 34 KB
    unsigned short* As = (unsigned short*)smem;              // [64][40]
    unsigned short* Bs = (unsigned short*)(smem + 1280);     // [256][40]
    int t = threadIdx.x;
    int row0 = blockIdx.x * 64;
    int lane = t & 63, wave = t >> 6;
    int wrow = (wave >> 1) * 32, wcol = (wave & 1) * 128;
    int quad = lane >> 4, l15 = lane & 15;
    f32x4 acc[2][8] = {};
    for (int k0 = 0; k0 < 256; k0 += 32) {
        #pragma unroll
        for (int p = 0; p < 2; ++p) {
            int li = t + p * 256;
            int r = li >> 3, kq = li & 7;
            float4 x4 = make_float4(0.f, 0.f, 0.f, 0.f);
            if (row0 + r < R) x4 = *(const float4*)&A[(size_t)(row0 + r) * 256 + k0 + kq * 4];
            ushort4 u;
            u.x = f2bf(x4.x); u.y = f2bf(x4.y); u.z = f2bf(x4.z); u.w = f2bf(x4.w);
            *(ushort4*)&As[r * 40 + kq * 4] = u;
        }
        #pragma unroll
        for (int p = 0; p < 4; ++p) {
            int li = t + p * 256;
            int c = li >> 2, q = li & 3;
            *(ushort8v*)&Bs[c * 40 + q * 8] = *(const ushort8v*)&Bt[(size_t)c * 256 + k0 + q * 8];
        }
        __syncthreads();
        short8v a[2], b[8];
        #pragma unroll
        for (int mi = 0; mi < 2; ++mi)
            a[mi] = *(const short8v*)&As[(wrow + mi * 16 + l15) * 40 + quad * 8];
        #pragma unroll
        for (int ni = 0; ni < 8; ++ni)
            b[ni] = *(const short8v*)&Bs[(wcol + ni * 16 + l15) * 40 + quad * 8];
        #pragma unroll
        for (int mi = 0; mi < 2; ++mi)
            #pragma unroll
            for (int ni = 0; ni < 8; ++ni)
                acc[mi][ni] = __builtin_amdgcn_mfma_f32_16x16x32_bf16(a[mi], b[ni], acc[mi][ni], 0, 0, 0);
        __syncthreads();
    }
    for (int half = 0; half < 2; ++half) {
        if ((wave & 1) == half) {
            #pragma unroll
            for (int mi = 0; mi < 2; ++mi)
                #pragma unroll
                for (int ni = 0; ni < 8; ++ni)
                    #pragma unroll
                    for (int rg = 0; rg < 4; ++rg)
                        smem[(wrow + mi * 16 + quad * 4 + rg) * 133 + ni * 16 + l15] = acc[mi][ni][rg];
        }
        __syncthreads();
        {
            int r = t & 63, hd = t >> 6;
            int hgl = half * 4 + hd;
            float psn = 0.f, psh = 0.f;
            #pragma unroll
            for (int j = 0; j < 32; ++j) {
                float cv = smem[r * 133 + hd * 32 + j];
                psn += cv * att1[hgl * 64 + j];
                psh += cv * att1[hgl * 64 + 32 + j];
            }
            if (row0 + r < R) {
                sns[(size_t)(row0 + r) * 16 + hgl] = psn;
                sns[(size_t)(row0 + r) * 16 + 8 + hgl] = psh;
            }
        }
        {
            int r2 = t >> 2, c0 = (t & 3) * 32;
            if (row0 + r2 < R) {
                unsigned int buf[16];
                #pragma unroll
                for (int j = 0; j < 16; ++j)
                    buf[j] = packbf2(smem[r2 * 133 + c0 + 2 * j], smem[r2 * 133 + c0 + 2 * j + 1]);
                size_t base = (size_t)(row0 + r2) * 256 + half * 128 + c0;
                *(ushort8v*)&Cbf[base]      = *(ushort8v*)&buf[0];
                *(ushort8v*)&Cbf[base + 8]  = *(ushort8v*)&buf[4];
                *(ushort8v*)&Cbf[base + 16] = *(ushort8v*)&buf[8];
                *(ushort8v*)&Cbf[base + 24] = *(ushort8v*)&buf[12];
            }
        }
        __syncthreads();
    }
}

// ---------------- conv1 fused per-hedge ----------------
__global__ __launch_bounds__(256) void hedge_fused1(const unsigned short* __restrict__ xl,
        const float* __restrict__ sns,
        const int* __restrict__ ncol, const int* __restrict__ pnh, const int* __restrict__ offs,
        float* __restrict__ alpha_csr, unsigned short* __restrict__ edge_out) {
    __shared__ int nl[1024];
    __shared__ float ssc[256 * 8];
    __shared__ float red[256];
    __shared__ float shB[256];
    __shared__ float shv8[8], mh8[8], inv8[8];
    int m = blockIdx.x;
    int beg = offs[m], d = offs[m + 1] - beg;
    int t = threadIdx.x;
    for (int i = t; i < d; i += 256) nl[i] = ncol[beg + i];
    __syncthreads();
    int h = t & 7, sl = t >> 3;
    float sv = 0.f;
    for (int i = sl; i < d; i += 32) sv += sns[(size_t)nl[i] * 16 + 8 + h];
    red[t] = sv; __syncthreads();
    for (int s2 = 16; s2; s2 >>= 1) { if (sl < s2) red[t] += red[t + s2 * 8]; __syncthreads(); }
    if (t < 8) shv8[t] = red[t];
    __syncthreads();
    float shvh = shv8[h];
    float pm = -1e30f;
    for (int i = sl; i < d; i += 32) {
        float s = lrelu(sns[(size_t)nl[i] * 16 + h] + shvh);
        if (i < 256) ssc[i * 8 + h] = s;
        pm = fmaxf(pm, s);
    }
    red[t] = pm; __syncthreads();
    for (int s2 = 16; s2; s2 >>= 1) { if (sl < s2) red[t] = fmaxf(red[t], red[t + s2 * 8]); __syncthreads(); }
    if (t < 8) mh8[t] = red[t];
    __syncthreads();
    float mh = mh8[h];
    float ps = 0.f;
    for (int i = sl; i < d; i += 32) {
        float s = (i < 256) ? ssc[i * 8 + h] : lrelu(sns[(size_t)nl[i] * 16 + h] + shvh);
        ps += __expf(s - mh);
    }
    red[t] = ps; __syncthreads();
    for (int s2 = 16; s2; s2 >>= 1) { if (sl < s2) red[t] += red[t + s2 * 8]; __syncthreads(); }
    if (t < 8) inv8[t] = 1.0f / (red[t] + 1e-16f);
    __syncthreads();
    float iv = inv8[h];
    for (int i = sl; i < d; i += 32) {
        float s = (i < 256) ? ssc[i * 8 + h] : lrelu(sns[(size_t)nl[i] * 16 + h] + shvh);
        float a = __expf(s - mh) * iv;
        if (i < 256) ssc[i * 8 + h] = a;
        alpha_csr[(size_t)pnh[beg + i] * 8 + h] = a;
    }
    __syncthreads();
    // weighted xl gather -> edge_out, unrolled x2 for MLP
    int c2 = t & 127, rs = t >> 7, hh = c2 >> 4;
    float mh2 = mh8[hh], iv2 = inv8[hh], sv2 = shv8[hh];
    float a0 = 0.f, a1 = 0.f;
    int i = rs;
    for (; i + 2 < d; i += 4) {
        int n0 = nl[i], n1 = nl[i + 2];
        float aA = (i < 256) ? ssc[i * 8 + hh]
                 : __expf(lrelu(sns[(size_t)n0 * 16 + hh] + sv2) - mh2) * iv2;
        float aB = (i + 2 < 256) ? ssc[(i + 2) * 8 + hh]
                 : __expf(lrelu(sns[(size_t)n1 * 16 + hh] + sv2) - mh2) * iv2;
        unsigned int uA = *(const unsigned int*)&xl[(size_t)n0 * 256 + c2 * 2];
        unsigned int uB = *(const unsigned int*)&xl[(size_t)n1 * 256 + c2 * 2];
        a0 += aA * bflo(uA) + aB * bflo(uB);
        a1 += aA * bfhi(uA) + aB * bfhi(uB);
    }
    for (; i < d; i += 2) {
        int n0 = nl[i];
        float aA = (i < 256) ? ssc[i * 8 + hh]
                 : __expf(lrelu(sns[(size_t)n0 * 16 + hh] + sv2) - mh2) * iv2;
        unsigned int uA = *(const unsigned int*)&xl[(size_t)n0 * 256 + c2 * 2];
        a0 += aA * bflo(uA);
        a1 += aA * bfhi(uA);
    }
    red[t] = a0; shB[t] = a1;
    __syncthreads();
    if (t < 128) {
        float Bv = d ? 1.0f / (float)d : 0.0f;
        float c0 = (red[t] + red[t + 128]) * Bv;
        float c1 = (shB[t] + shB[t + 128]) * Bv;
        ((unsigned int*)edge_out)[(size_t)m * 128 + t] = packbf2(c0, c1);
    }
}

// ---------------- fused conv1-node-agg + conv2 GEMM: 16 nodes/block ----------------
// stage1: h[n,:] = relu(D * sum_p alpha*edge_out[mcol[p],:] + b1)  (LDS only)
// stage2: xl2 = h @ W2, sns2 = (xl2 . att2_n, xl2 . att2_h)
#define ALS 264
__global__ __launch_bounds__(256) void node_conv2_fused(const unsigned short* __restrict__ edge_out,
        const float* __restrict__ alpha_csr, const int* __restrict__ mcol,
        const int* __restrict__ offs, const float* __restrict__ b1,
        const float* __restrict__ W2, const float* __restrict__ att2,
        float* __restrict__ xl2, float2* __restrict__ sns2) {
    __shared__ float W2L[4096];
    __shared__ unsigned short AL[16 * ALS];
    __shared__ float b1L[256];
    int t = threadIdx.x;
    for (int i = t; i < 4096; i += 256) W2L[i] = W2[i];
    if (t < 256) b1L[t] = b1[t];
    int r = t >> 4, c = t & 15;
    int n = blockIdx.x * 16 + r;
    int beg = offs[n], end = offs[n + 1];
    int h = c >> 1;                         // head of channels [c*16, c*16+16)
    float acc[16] = {};
    int p = beg;
    for (; p + 1 < end; p += 2) {
        float aA = alpha_csr[(size_t)p * 8 + h];
        float aB = alpha_csr[(size_t)(p + 1) * 8 + h];
        int m0 = mcol[p], m1 = mcol[p + 1];
        ushort8v u0a = *(const ushort8v*)&edge_out[(size_t)m0 * 256 + c * 16];
        ushort8v u0b = *(const ushort8v*)&edge_out[(size_t)m0 * 256 + c * 16 + 8];
        ushort8v u1a = *(const ushort8v*)&edge_out[(size_t)m1 * 256 + c * 16];
        ushort8v u1b = *(const ushort8v*)&edge_out[(size_t)m1 * 256 + c * 16 + 8];
        #pragma unroll
        for (int j = 0; j < 8; ++j) {
            acc[j]     += aA * bf1((unsigned short)u0a[j]) + aB * bf1((unsigned short)u1a[j]);
            acc[j + 8] += aA * bf1((unsigned short)u0b[j]) + aB * bf1((unsigned short)u1b[j]);
        }
    }
    if (p < end) {
        float aA = alpha_csr[(size_t)p * 8 + h];
        int m0 = mcol[p];
        ushort8v u0a = *(const ushort8v*)&edge_out[(size_t)m0 * 256 + c * 16];
        ushort8v u0b = *(const ushort8v*)&edge_out[(size_t)m0 * 256 + c * 16 + 8];
        #pragma unroll
        for (int j = 0; j < 8; ++j) {
            acc[j]     += aA * bf1((unsigned short)u0a[j]);
            acc[j + 8] += aA * bf1((unsigned short)u0b[j]);
        }
    }
    __syncthreads();   // W2L/b1L ready; also AL safe to write
    int dd = end - beg;
    float D = dd ? 1.0f / (float)dd : 0.0f;
    {
        unsigned short tmp[16];
        #pragma unroll
        for (int j = 0; j < 16; ++j) {
            float v = acc[j] * D + b1L[c * 16 + j];
            tmp[j] = f2bf(v > 0.f ? v : 0.f);
        }
        *(ushort8v*)&AL[r * ALS + c * 16]     = *(ushort8v*)&tmp[0];
        *(ushort8v*)&AL[r * ALS + c * 16 + 8] = *(ushort8v*)&tmp[8];
    }
    __syncthreads();
    // stage2: GEMM 16x16 over K=256
    float acc2 = 0.f;
    for (int k = 0; k < 256; k += 4) {
        ushort4 av = *(const ushort4*)&AL[r * ALS + k];
        acc2 += bf1(av.x) * W2L[k * 16 + c] + bf1(av.y) * W2L[(k + 1) * 16 + c]
              + bf1(av.z) * W2L[(k + 2) * 16 + c] + bf1(av.w) * W2L[(k + 3) * 16 + c];
    }
    float svn = acc2 * att2[c];
    float svh = acc2 * att2[16 + c];
    #pragma unroll
    for (int s = 8; s; s >>= 1) { svn += __shfl_xor(svn, s); svh += __shfl_xor(svh, s); }
    xl2[(size_t)n * 16 + c] = acc2;
    if (c == 0) sns2[n] = make_float2(svn, svh);
}

// ---------------- conv2 fused per-hedge ----------------
__global__ __launch_bounds__(256) void hedge_fused2(const float* __restrict__ xl2,
        const float2* __restrict__ sns2,
        const int* __restrict__ ncol, const int* __restrict__ pnh, const int* __restrict__ offs,
        float* __restrict__ alpha2, float* __restrict__ edge_out2) {
    __shared__ int nl[1024];
    __shared__ float ssc[1024];
    __shared__ float red[256];
    __shared__ float sh_s, mh_s, inv_s;
    int m = blockIdx.x;
    int beg = offs[m], d = offs[m + 1] - beg;
    int t = threadIdx.x;
    for (int i = t; i < d; i += 256) nl[i] = ncol[beg + i];
    __syncthreads();
    float sv = 0.f;
    for (int i = t; i < d; i += 256) {
        float2 v = sns2[nl[i]];
        ssc[i] = v.x;
        sv += v.y;
    }
    red[t] = sv; __syncthreads();
    for (int s2 = 128; s2; s2 >>= 1) { if (t < s2) red[t] += red[t + s2]; __syncthreads(); }
    if (t == 0) sh_s = red[0];
    __syncthreads();
    float sh = sh_s;
    float pm = -1e30f;
    for (int i = t; i < d; i += 256) {
        float s = lrelu(ssc[i] + sh);
        ssc[i] = s;
        pm = fmaxf(pm, s);
    }
    red[t] = pm; __syncthreads();
    for (int s2 = 128; s2; s2 >>= 1) { if (t < s2) red[t] = fmaxf(red[t], red[t + s2]); __syncthreads(); }
    if (t == 0) mh_s = red[0];
    __syncthreads();
    float mh = mh_s;
    float ps = 0.f;
    for (int i = t; i < d; i += 256) ps += __expf(ssc[i] - mh);
    red[t] = ps; __syncthreads();
    for (int s2 = 128; s2; s2 >>= 1) { if (t < s2) red[t] += red[t + s2]; __syncthreads(); }
    if (t == 0) inv_s = 1.0f / (red[0] + 1e-16f);
    __syncthreads();
    float inv = inv_s;
    for (int i = t; i < d; i += 256) {
        float a = __expf(ssc[i] - mh) * inv;
        ssc[i] = a;
        alpha2[pnh[beg + i]] = a;
    }
    __syncthreads();
    int ip = t >> 4, c = t & 15;
    float acc = 0.f;
    for (int i = ip; i < d; i += 16) acc += ssc[i] * xl2[(size_t)nl[i] * 16 + c];
    red[t] = acc; __syncthreads();
    for (int s2 = 8; s2; s2 >>= 1) { if (ip < s2) red[t] += red[t + s2 * 16]; __syncthreads(); }
    if (t < 16) {
        float Bv = d ? 1.0f / (float)d : 0.0f;
        edge_out2[(size_t)m * 16 + t] = red[t] * Bv;
    }
}

// ---------------- conv2 node aggregation + log_softmax: 16 nodes/block ----------------
__global__ __launch_bounds__(256) void node_out2b(const float* __restrict__ edge_out2,
        const float* __restrict__ alpha2, const int* __restrict__ mcol,
        const int* __restrict__ offs, const float* __restrict__ b2, float* __restrict__ out) {
    int t = threadIdx.x;
    int n = blockIdx.x * 16 + (t >> 4);
    int c = t & 15;
    int beg = offs[n], end = offs[n + 1];
    float acc = 0.f;
    int p = beg;
    for (; p + 1 < end; p += 2) {
        float aA = alpha2[p], aB = alpha2[p + 1];
        int m0 = mcol[p], m1 = mcol[p + 1];
        acc += aA * edge_out2[(size_t)m0 * 16 + c] + aB * edge_out2[(size_t)m1 * 16 + c];
    }
    if (p < end) acc += alpha2[p] * edge_out2[(size_t)mcol[p] * 16 + c];
    int dd = end - beg;
    float D = dd ? 1.0f / (float)dd : 0.0f;
    float v = acc * D + b2[c];
    float mx = v;
    #pragma unroll
    for (int s = 8; s; s >>= 1) mx = fmaxf(mx, __shfl_xor(mx, s));
    float ex = __expf(v - mx);
    float sm = ex;
    #pragma unroll
    for (int s = 8; s; s >>= 1) sm += __shfl_xor(sm, s);
    out[(size_t)n * 16 + c] = (v - mx) - logf(sm);
}

extern "C" void kernel_launch(void* const* d_in, const int* in_sizes, int n_in,
                              void* d_out, int out_size, void* d_ws, size_t ws_size,
                              hipStream_t stream) {
    const float* x        = (const float*)d_in[0];
    const int*   node_idx = (const int*)d_in[1];
    const int*   hedge_idx= (const int*)d_in[2];
    const float* W1       = (const float*)d_in[3];
    const float* att1     = (const float*)d_in[4];
    const float* b1       = (const float*)d_in[5];
    const float* W2       = (const float*)d_in[6];
    const float* att2     = (const float*)d_in[7];
    const float* b2       = (const float*)d_in[8];
    float* out = (float*)d_out;

    char* w = (char*)d_ws;
    auto carve = [&](size_t bytes) -> char* {
        char* p = w;
        w += (bytes + 255) & ~(size_t)255;
        return p;
    };
    int* deg_node  = (int*)carve((size_t)NN * 4);
    int* deg_hedge = (int*)carve((size_t)NM * 4);
    int* cnt_node  = (int*)carve((size_t)NN * 4);
    int* cnt_hedge = (int*)carve((size_t)NM * 4);
    char* zero_end = w;
    int* node_off  = (int*)carve((size_t)(NN + 1) * 4);
    int* hedge_off = (int*)carve((size_t)(NM + 1) * 4);
    int* bsum_n    = (int*)carve(64 * 4);
    int* bsum_h    = (int*)carve(64 * 4);
    int* mcol      = (int*)carve((size_t)NE * 4);
    int* ncol      = (int*)carve((size_t)NE * 4);
    int* pnh       = (int*)carve((size_t)NE * 4);
    unsigned short* W1t = (unsigned short*)carve((size_t)256 * 256 * 2);
    unsigned short* xl  = (unsigned short*)carve((size_t)NN * CD * 2);
    float* sns     = (float*)carve((size_t)NN * 16 * 4);
    float* alpha_csr = (float*)carve((size_t)NE * 8 * 4);
    unsigned short* edge_out = (unsigned short*)carve((size_t)NM * CD * 2);
    float* xl2     = (float*)carve((size_t)NN * C2 * 4);
    float2* sns2   = (float2*)carve((size_t)NN * 8);
    float* alpha2  = (float*)carve((size_t)NE * 4);
    float* edge_out2 = (float*)carve((size_t)NM * C2 * 4);

    hipMemsetAsync(d_ws, 0, (size_t)(zero_end - (char*)d_ws), stream);

    convW1_kernel<<<256, 256, 0, stream>>>(W1, W1t);
    count_deg_kernel<<<CDIV(NE, 256), 256, 0, stream>>>(node_idx, hedge_idx, deg_node, deg_hedge);

    int nbN = CDIV(NN, 1024), nbM = CDIV(NM, 1024);
    scan1_kernel<<<nbN, 1024, 0, stream>>>(deg_node, node_off, bsum_n, NN);
    scan2_kernel<<<1, 64, 0, stream>>>(bsum_n, nbN, node_off + NN);
    scan3_kernel<<<nbN, 1024, 0, stream>>>(node_off, bsum_n, NN);
    scan1_kernel<<<nbM, 1024, 0, stream>>>(deg_hedge, hedge_off, bsum_h, NM);
    scan2_kernel<<<1, 64, 0, stream>>>(bsum_h, nbM, hedge_off + NM);
    scan3_kernel<<<nbM, 1024, 0, stream>>>(hedge_off, bsum_h, NM);

    fill_kernel<<<CDIV(NE, 256), 256, 0, stream>>>(node_idx, hedge_idx, node_off, hedge_off,
                                                   cnt_node, cnt_hedge, mcol, ncol, pnh);

    // ---- conv1 ----
    gemm256_mfma<<<CDIV(NN, 64), 256, 0, stream>>>(x, W1t, att1, xl, sns, NN);
    hedge_fused1<<<NM, 256, 0, stream>>>(xl, sns, ncol, pnh, hedge_off, alpha_csr, edge_out);

    // ---- conv1 node agg + conv2 GEMM fused ----
    node_conv2_fused<<<CDIV(NN, 16), 256, 0, stream>>>(edge_out, alpha_csr, mcol, node_off,
                                                       b1, W2, att2, xl2, sns2);

    // ---- conv2 ----
    hedge_fused2<<<NM, 256, 0, stream>>>(xl2, sns2, ncol, pnh, hedge_off, alpha2, edge_out2);
    node_out2b<<<CDIV(NN, 16), 256, 0, stream>>>(edge_out2, alpha2, mcol, node_off, b2, out);
}

// Round 5
// 280.827 us; speedup vs baseline: 3.4354x; 1.0238x over previous
//
#include <hip/hip_runtime.h>
#include <hip/hip_bf16.h>
#include <math.h>

#define NN 50000
#define NM 10000
#define NE 400000
#define CD 256
#define C2 16

#define CDIV(a,b) (((a)+(b)-1)/(b))

typedef __attribute__((ext_vector_type(8))) short short8v;
typedef __attribute__((ext_vector_type(8))) unsigned short ushort8v;
typedef __attribute__((ext_vector_type(4))) float f32x4;

__device__ __forceinline__ float bflo(unsigned int u) { return __uint_as_float(u << 16); }
__device__ __forceinline__ float bfhi(unsigned int u) { return __uint_as_float(u & 0xffff0000u); }
__device__ __forceinline__ unsigned short f2bf(float f) {
    union { __hip_bfloat16 h; unsigned short u; } cv;
    cv.h = __float2bfloat16(f);
    return cv.u;
}
__device__ __forceinline__ unsigned int packbf2(float a, float b) {
    return (unsigned int)f2bf(a) | ((unsigned int)f2bf(b) << 16);
}
__device__ __forceinline__ float bf1(unsigned short u) { return __uint_as_float(((unsigned int)u) << 16); }
__device__ __forceinline__ float lrelu(float s) { return s > 0.f ? s : 0.2f * s; }

// ---------------- CSR build ----------------

__global__ void count_deg_kernel(const int* __restrict__ node_idx, const int* __restrict__ hedge_idx,
                                 int* __restrict__ deg_node, int* __restrict__ deg_hedge) {
    int e = blockIdx.x * 256 + threadIdx.x;
    if (e < NE) {
        atomicAdd(&deg_node[node_idx[e]], 1);
        atomicAdd(&deg_hedge[hedge_idx[e]], 1);
    }
}

__global__ __launch_bounds__(1024) void scan1_kernel(const int* __restrict__ deg, int* __restrict__ off,
                                                     int* __restrict__ bsum, int n) {
    __shared__ int lds[1024];
    int t = threadIdx.x, b = blockIdx.x;
    int i = b * 1024 + t;
    int v = (i < n) ? deg[i] : 0;
    lds[t] = v;
    __syncthreads();
    for (int s = 1; s < 1024; s <<= 1) {
        int tv = (t >= s) ? lds[t - s] : 0;
        __syncthreads();
        lds[t] += tv;
        __syncthreads();
    }
    if (i < n) off[i] = lds[t] - v;
    if (t == 1023) bsum[b] = lds[t];
}

__global__ void scan2_kernel(int* __restrict__ bsum, int nb, int* __restrict__ off_last) {
    __shared__ int s[64];
    int t = threadIdx.x;
    if (t < nb) s[t] = bsum[t];
    __syncthreads();
    if (t == 0) {
        int run = 0;
        for (int j = 0; j < nb; ++j) { int tmp = s[j]; s[j] = run; run += tmp; }
        *off_last = run;
    }
    __syncthreads();
    if (t < nb) bsum[t] = s[t];
}

__global__ __launch_bounds__(1024) void scan3_kernel(int* __restrict__ off, const int* __restrict__ bsum, int n) {
    int i = blockIdx.x * 1024 + threadIdx.x;
    if (i < n) off[i] += bsum[blockIdx.x];
}

__global__ void fill_kernel(const int* __restrict__ node_idx, const int* __restrict__ hedge_idx,
                            const int* __restrict__ node_off, const int* __restrict__ hedge_off,
                            int* __restrict__ cnt_node, int* __restrict__ cnt_hedge,
                            int* __restrict__ mcol, int* __restrict__ ncol, int* __restrict__ pnh) {
    int e = blockIdx.x * 256 + threadIdx.x;
    if (e < NE) {
        int n = node_idx[e];
        int m = hedge_idx[e];
        int p = node_off[n] + atomicAdd(&cnt_node[n], 1);
        int q = hedge_off[m] + atomicAdd(&cnt_hedge[m], 1);
        mcol[p] = m;
        ncol[q] = n;
        pnh[q] = p;
    }
}

// ---------------- W1 -> bf16 transposed [col][k] ----------------
__global__ void convW1_kernel(const float* __restrict__ W1, unsigned short* __restrict__ W1t) {
    int n = blockIdx.x, k = threadIdx.x;
    W1t[n * 256 + k] = f2bf(W1[k * 256 + n]);
}

// ---------------- MFMA GEMM: xl(bf16)[R,256] = A(f32)[R,256] @ W1; fused sn+snh into sns[R,16] ----------------
__global__ __launch_bounds__(256) void gemm256_mfma(const float* __restrict__ A,
        const unsigned short* __restrict__ Bt, const float* __restrict__ att1,
        unsigned short* __restrict__ Cbf, float* __restrict__ sns, int R) {
    __shared__ float smem[8512];                             // 34 KB
    unsigned short* As = (unsigned short*)smem;              // [64][40]
    unsigned short* Bs = (unsigned short*)(smem + 1280);     // [256][40]
    int t = threadIdx.x;
    int row0 = blockIdx.x * 64;
    int lane = t & 63, wave = t >> 6;
    int wrow = (wave >> 1) * 32, wcol = (wave & 1) * 128;
    int quad = lane >> 4, l15 = lane & 15;
    f32x4 acc[2][8] = {};
    for (int k0 = 0; k0 < 256; k0 += 32) {
        #pragma unroll
        for (int p = 0; p < 2; ++p) {
            int li = t + p * 256;
            int r = li >> 3, kq = li & 7;
            float4 x4 = make_float4(0.f, 0.f, 0.f, 0.f);
            if (row0 + r < R) x4 = *(const float4*)&A[(size_t)(row0 + r) * 256 + k0 + kq * 4];
            ushort4 u;
            u.x = f2bf(x4.x); u.y = f2bf(x4.y); u.z = f2bf(x4.z); u.w = f2bf(x4.w);
            *(ushort4*)&As[r * 40 + kq * 4] = u;
        }
        #pragma unroll
        for (int p = 0; p < 4; ++p) {
            int li = t + p * 256;
            int c = li >> 2, q = li & 3;
            *(ushort8v*)&Bs[c * 40 + q * 8] = *(const ushort8v*)&Bt[(size_t)c * 256 + k0 + q * 8];
        }
        __syncthreads();
        short8v a[2], b[8];
        #pragma unroll
        for (int mi = 0; mi < 2; ++mi)
            a[mi] = *(const short8v*)&As[(wrow + mi * 16 + l15) * 40 + quad * 8];
        #pragma unroll
        for (int ni = 0; ni < 8; ++ni)
            b[ni] = *(const short8v*)&Bs[(wcol + ni * 16 + l15) * 40 + quad * 8];
        #pragma unroll
        for (int mi = 0; mi < 2; ++mi)
            #pragma unroll
            for (int ni = 0; ni < 8; ++ni)
                acc[mi][ni] = __builtin_amdgcn_mfma_f32_16x16x32_bf16(a[mi], b[ni], acc[mi][ni], 0, 0, 0);
        __syncthreads();
    }
    for (int half = 0; half < 2; ++half) {
        if ((wave & 1) == half) {
            #pragma unroll
            for (int mi = 0; mi < 2; ++mi)
                #pragma unroll
                for (int ni = 0; ni < 8; ++ni)
                    #pragma unroll
                    for (int rg = 0; rg < 4; ++rg)
                        smem[(wrow + mi * 16 + quad * 4 + rg) * 133 + ni * 16 + l15] = acc[mi][ni][rg];
        }
        __syncthreads();
        {
            int r = t & 63, hd = t >> 6;
            int hgl = half * 4 + hd;
            float psn = 0.f, psh = 0.f;
            #pragma unroll
            for (int j = 0; j < 32; ++j) {
                float cv = smem[r * 133 + hd * 32 + j];
                psn += cv * att1[hgl * 64 + j];
                psh += cv * att1[hgl * 64 + 32 + j];
            }
            if (row0 + r < R) {
                sns[(size_t)(row0 + r) * 16 + hgl] = psn;
                sns[(size_t)(row0 + r) * 16 + 8 + hgl] = psh;
            }
        }
        {
            int r2 = t >> 2, c0 = (t & 3) * 32;
            if (row0 + r2 < R) {
                unsigned int buf[16];
                #pragma unroll
                for (int j = 0; j < 16; ++j)
                    buf[j] = packbf2(smem[r2 * 133 + c0 + 2 * j], smem[r2 * 133 + c0 + 2 * j + 1]);
                size_t base = (size_t)(row0 + r2) * 256 + half * 128 + c0;
                *(ushort8v*)&Cbf[base]      = *(ushort8v*)&buf[0];
                *(ushort8v*)&Cbf[base + 8]  = *(ushort8v*)&buf[4];
                *(ushort8v*)&Cbf[base + 16] = *(ushort8v*)&buf[8];
                *(ushort8v*)&Cbf[base + 24] = *(ushort8v*)&buf[12];
            }
        }
        __syncthreads();
    }
}

// ---------------- conv1 fused per-hedge ----------------
// pass0: single float4 sweep of sns rows -> sn cached in LDS, snh summed per head
// then max/exp-sum/alpha fully in LDS; pass B: 16B xl loads, 8 rows parallel x2 unroll
__global__ __launch_bounds__(256) void hedge_fused1(const unsigned short* __restrict__ xl,
        const float* __restrict__ sns,
        const int* __restrict__ ncol, const int* __restrict__ pnh, const int* __restrict__ offs,
        float* __restrict__ alpha_csr, unsigned short* __restrict__ edge_out) {
    __shared__ int nl[1024];
    __shared__ float ssc[2048];     // [256 rows][8 heads]; later aliased as pass-B reduce
    __shared__ float red[256];
    __shared__ float redH[512];     // [64 slots][8 heads]
    __shared__ float shv8[8], mh8[8], inv8[8];
    int m = blockIdx.x;
    int beg = offs[m], d = offs[m + 1] - beg;
    int t = threadIdx.x;
    for (int i = t; i < d; i += 256) nl[i] = ncol[beg + i];
    __syncthreads();
    // ---- pass 0: merged sns sweep ----
    {
        int q = t & 3, i0 = t >> 2;   // 64 rows in parallel, 4 threads/row (16B each)
        float4 hs = make_float4(0.f, 0.f, 0.f, 0.f);
        for (int i = i0; i < d; i += 64) {
            float4 v = *(const float4*)&sns[(size_t)nl[i] * 16 + q * 4];
            if (q < 2) {
                if (i < 256) *(float4*)&ssc[i * 8 + q * 4] = v;
            } else {
                hs.x += v.x; hs.y += v.y; hs.z += v.z; hs.w += v.w;
            }
        }
        if (q >= 2) *(float4*)&redH[(i0 * 8) + (q - 2) * 4] = hs;
    }
    __syncthreads();
    // reduce redH (64 slots x 8 heads, flat with stride multiple of 8)
    if (t < 256) redH[t] += redH[t + 256];
    __syncthreads();
    for (int s = 128; s >= 8; s >>= 1) {
        if (t < s) redH[t] += redH[t + s];
        __syncthreads();
    }
    if (t < 8) shv8[t] = redH[t];
    __syncthreads();
    int h = t & 7, sl = t >> 3;
    float shvh = shv8[h];
    // ---- max (scores -> ssc) ----
    float pm = -1e30f;
    for (int i = sl; i < d; i += 32) {
        float sv = (i < 256) ? ssc[i * 8 + h] : sns[(size_t)nl[i] * 16 + h];
        float s = lrelu(sv + shvh);
        if (i < 256) ssc[i * 8 + h] = s;
        pm = fmaxf(pm, s);
    }
    red[t] = pm; __syncthreads();
    for (int s2 = 16; s2; s2 >>= 1) { if (sl < s2) red[t] = fmaxf(red[t], red[t + s2 * 8]); __syncthreads(); }
    if (t < 8) mh8[t] = red[t];
    __syncthreads();
    float mh = mh8[h];
    // ---- exp-sum (exps -> ssc) ----
    float ps = 0.f;
    for (int i = sl; i < d; i += 32) {
        float s = (i < 256) ? ssc[i * 8 + h] : lrelu(sns[(size_t)nl[i] * 16 + h] + shvh);
        float e = __expf(s - mh);
        if (i < 256) ssc[i * 8 + h] = e;
        ps += e;
    }
    red[t] = ps; __syncthreads();
    for (int s2 = 16; s2; s2 >>= 1) { if (sl < s2) red[t] += red[t + s2 * 8]; __syncthreads(); }
    if (t < 8) inv8[t] = 1.0f / (red[t] + 1e-16f);
    __syncthreads();
    float iv = inv8[h];
    // ---- alpha (-> ssc, scatter to node-CSR) ----
    for (int i = sl; i < d; i += 32) {
        float a;
        if (i < 256) { a = ssc[i * 8 + h] * iv; ssc[i * 8 + h] = a; }
        else a = __expf(lrelu(sns[(size_t)nl[i] * 16 + h] + shvh) - mh) * iv;
        alpha_csr[(size_t)pnh[beg + i] * 8 + h] = a;
    }
    __syncthreads();
    // ---- pass B: weighted xl gather, 16B loads, 8 row-slots, x2 unroll ----
    int lane32 = t & 31, rs8 = t >> 5;
    int c8 = lane32 * 8;
    int hh = lane32 >> 2;
    float mh2 = mh8[hh], iv2 = inv8[hh], sv2 = shv8[hh];
    float acc8[8] = {};
    int i = rs8;
    for (; i + 8 < d; i += 16) {
        int n0 = nl[i], n1 = nl[i + 8];
        float aA = (i < 256) ? ssc[i * 8 + hh]
                 : __expf(lrelu(sns[(size_t)n0 * 16 + hh] + sv2) - mh2) * iv2;
        float aB = (i + 8 < 256) ? ssc[(i + 8) * 8 + hh]
                 : __expf(lrelu(sns[(size_t)n1 * 16 + hh] + sv2) - mh2) * iv2;
        ushort8v uA = *(const ushort8v*)&xl[(size_t)n0 * 256 + c8];
        ushort8v uB = *(const ushort8v*)&xl[(size_t)n1 * 256 + c8];
        #pragma unroll
        for (int j = 0; j < 8; ++j)
            acc8[j] += aA * bf1((unsigned short)uA[j]) + aB * bf1((unsigned short)uB[j]);
    }
    for (; i < d; i += 8) {
        int n0 = nl[i];
        float aA = (i < 256) ? ssc[i * 8 + hh]
                 : __expf(lrelu(sns[(size_t)n0 * 16 + hh] + sv2) - mh2) * iv2;
        ushort8v uA = *(const ushort8v*)&xl[(size_t)n0 * 256 + c8];
        #pragma unroll
        for (int j = 0; j < 8; ++j)
            acc8[j] += aA * bf1((unsigned short)uA[j]);
    }
    __syncthreads();            // everyone done reading ssc alphas
    float* redA = ssc;          // alias: [8 slots][32 lanes][8 ch] = 2048 floats
    *(float4*)&redA[t * 8]     = make_float4(acc8[0], acc8[1], acc8[2], acc8[3]);
    *(float4*)&redA[t * 8 + 4] = make_float4(acc8[4], acc8[5], acc8[6], acc8[7]);
    __syncthreads();
    for (int s = 4; s >= 1; s >>= 1) {
        if (rs8 < s) {
            #pragma unroll
            for (int j = 0; j < 8; ++j) redA[t * 8 + j] += redA[(t + s * 32) * 8 + j];
        }
        __syncthreads();
    }
    if (t < 32) {
        float Bv = d ? 1.0f / (float)d : 0.0f;
        unsigned int buf[4];
        #pragma unroll
        for (int j = 0; j < 4; ++j)
            buf[j] = packbf2(redA[t * 8 + 2 * j] * Bv, redA[t * 8 + 2 * j + 1] * Bv);
        *(ushort8v*)&edge_out[(size_t)m * 256 + t * 8] = *(ushort8v*)&buf[0];
    }
}

// ---------------- fused conv1-node-agg + conv2 GEMM: 16 nodes/block ----------------
#define ALS 264
__global__ __launch_bounds__(256) void node_conv2_fused(const unsigned short* __restrict__ edge_out,
        const float* __restrict__ alpha_csr, const int* __restrict__ mcol,
        const int* __restrict__ offs, const float* __restrict__ b1,
        const float* __restrict__ W2, const float* __restrict__ att2,
        float* __restrict__ xl2, float2* __restrict__ sns2) {
    __shared__ float W2L[4096];
    __shared__ unsigned short AL[16 * ALS];
    __shared__ float b1L[256];
    int t = threadIdx.x;
    for (int i = t; i < 4096; i += 256) W2L[i] = W2[i];
    if (t < 256) b1L[t] = b1[t];
    int r = t >> 4, c = t & 15;
    int n = blockIdx.x * 16 + r;
    int beg = offs[n], end = offs[n + 1];
    int h = c >> 1;
    float acc[16] = {};
    int p = beg;
    for (; p + 3 < end; p += 4) {
        float aA = alpha_csr[(size_t)p * 8 + h];
        float aB = alpha_csr[(size_t)(p + 1) * 8 + h];
        float aC = alpha_csr[(size_t)(p + 2) * 8 + h];
        float aD = alpha_csr[(size_t)(p + 3) * 8 + h];
        int m0 = mcol[p], m1 = mcol[p + 1], m2 = mcol[p + 2], m3 = mcol[p + 3];
        ushort8v u0a = *(const ushort8v*)&edge_out[(size_t)m0 * 256 + c * 16];
        ushort8v u0b = *(const ushort8v*)&edge_out[(size_t)m0 * 256 + c * 16 + 8];
        ushort8v u1a = *(const ushort8v*)&edge_out[(size_t)m1 * 256 + c * 16];
        ushort8v u1b = *(const ushort8v*)&edge_out[(size_t)m1 * 256 + c * 16 + 8];
        ushort8v u2a = *(const ushort8v*)&edge_out[(size_t)m2 * 256 + c * 16];
        ushort8v u2b = *(const ushort8v*)&edge_out[(size_t)m2 * 256 + c * 16 + 8];
        ushort8v u3a = *(const ushort8v*)&edge_out[(size_t)m3 * 256 + c * 16];
        ushort8v u3b = *(const ushort8v*)&edge_out[(size_t)m3 * 256 + c * 16 + 8];
        #pragma unroll
        for (int j = 0; j < 8; ++j) {
            acc[j]     += aA * bf1((unsigned short)u0a[j]) + aB * bf1((unsigned short)u1a[j])
                        + aC * bf1((unsigned short)u2a[j]) + aD * bf1((unsigned short)u3a[j]);
            acc[j + 8] += aA * bf1((unsigned short)u0b[j]) + aB * bf1((unsigned short)u1b[j])
                        + aC * bf1((unsigned short)u2b[j]) + aD * bf1((unsigned short)u3b[j]);
        }
    }
    for (; p < end; ++p) {
        float aA = alpha_csr[(size_t)p * 8 + h];
        int m0 = mcol[p];
        ushort8v u0a = *(const ushort8v*)&edge_out[(size_t)m0 * 256 + c * 16];
        ushort8v u0b = *(const ushort8v*)&edge_out[(size_t)m0 * 256 + c * 16 + 8];
        #pragma unroll
        for (int j = 0; j < 8; ++j) {
            acc[j]     += aA * bf1((unsigned short)u0a[j]);
            acc[j + 8] += aA * bf1((unsigned short)u0b[j]);
        }
    }
    __syncthreads();
    int dd = end - beg;
    float D = dd ? 1.0f / (float)dd : 0.0f;
    {
        unsigned short tmp[16];
        #pragma unroll
        for (int j = 0; j < 16; ++j) {
            float v = acc[j] * D + b1L[c * 16 + j];
            tmp[j] = f2bf(v > 0.f ? v : 0.f);
        }
        *(ushort8v*)&AL[r * ALS + c * 16]     = *(ushort8v*)&tmp[0];
        *(ushort8v*)&AL[r * ALS + c * 16 + 8] = *(ushort8v*)&tmp[8];
    }
    __syncthreads();
    float acc2 = 0.f;
    for (int k = 0; k < 256; k += 4) {
        ushort4 av = *(const ushort4*)&AL[r * ALS + k];
        acc2 += bf1(av.x) * W2L[k * 16 + c] + bf1(av.y) * W2L[(k + 1) * 16 + c]
              + bf1(av.z) * W2L[(k + 2) * 16 + c] + bf1(av.w) * W2L[(k + 3) * 16 + c];
    }
    float svn = acc2 * att2[c];
    float svh = acc2 * att2[16 + c];
    #pragma unroll
    for (int s = 8; s; s >>= 1) { svn += __shfl_xor(svn, s); svh += __shfl_xor(svh, s); }
    xl2[(size_t)n * 16 + c] = acc2;
    if (c == 0) sns2[n] = make_float2(svn, svh);
}

// ---------------- conv2 fused per-hedge ----------------
__global__ __launch_bounds__(256) void hedge_fused2(const float* __restrict__ xl2,
        const float2* __restrict__ sns2,
        const int* __restrict__ ncol, const int* __restrict__ pnh, const int* __restrict__ offs,
        float* __restrict__ alpha2, float* __restrict__ edge_out2) {
    __shared__ int nl[1024];
    __shared__ float ssc[1024];
    __shared__ float red[256];
    __shared__ float sh_s, mh_s, inv_s;
    int m = blockIdx.x;
    int beg = offs[m], d = offs[m + 1] - beg;
    int t = threadIdx.x;
    for (int i = t; i < d; i += 256) nl[i] = ncol[beg + i];
    __syncthreads();
    float sv = 0.f;
    for (int i = t; i < d; i += 256) {
        float2 v = sns2[nl[i]];
        ssc[i] = v.x;
        sv += v.y;
    }
    red[t] = sv; __syncthreads();
    for (int s2 = 128; s2; s2 >>= 1) { if (t < s2) red[t] += red[t + s2]; __syncthreads(); }
    if (t == 0) sh_s = red[0];
    __syncthreads();
    float sh = sh_s;
    float pm = -1e30f;
    for (int i = t; i < d; i += 256) {
        float s = lrelu(ssc[i] + sh);
        ssc[i] = s;
        pm = fmaxf(pm, s);
    }
    red[t] = pm; __syncthreads();
    for (int s2 = 128; s2; s2 >>= 1) { if (t < s2) red[t] = fmaxf(red[t], red[t + s2]); __syncthreads(); }
    if (t == 0) mh_s = red[0];
    __syncthreads();
    float mh = mh_s;
    float ps = 0.f;
    for (int i = t; i < d; i += 256) ps += __expf(ssc[i] - mh);
    red[t] = ps; __syncthreads();
    for (int s2 = 128; s2; s2 >>= 1) { if (t < s2) red[t] += red[t + s2]; __syncthreads(); }
    if (t == 0) inv_s = 1.0f / (red[0] + 1e-16f);
    __syncthreads();
    float inv = inv_s;
    for (int i = t; i < d; i += 256) {
        float a = __expf(ssc[i] - mh) * inv;
        ssc[i] = a;
        alpha2[pnh[beg + i]] = a;
    }
    __syncthreads();
    int ip = t >> 4, c = t & 15;
    float acc = 0.f;
    for (int i = ip; i < d; i += 16) acc += ssc[i] * xl2[(size_t)nl[i] * 16 + c];
    red[t] = acc; __syncthreads();
    for (int s2 = 8; s2; s2 >>= 1) { if (ip < s2) red[t] += red[t + s2 * 16]; __syncthreads(); }
    if (t < 16) {
        float Bv = d ? 1.0f / (float)d : 0.0f;
        edge_out2[(size_t)m * 16 + t] = red[t] * Bv;
    }
}

// ---------------- conv2 node aggregation + log_softmax: 16 nodes/block ----------------
__global__ __launch_bounds__(256) void node_out2b(const float* __restrict__ edge_out2,
        const float* __restrict__ alpha2, const int* __restrict__ mcol,
        const int* __restrict__ offs, const float* __restrict__ b2, float* __restrict__ out) {
    int t = threadIdx.x;
    int n = blockIdx.x * 16 + (t >> 4);
    int c = t & 15;
    int beg = offs[n], end = offs[n + 1];
    float acc = 0.f;
    int p = beg;
    for (; p + 1 < end; p += 2) {
        float aA = alpha2[p], aB = alpha2[p + 1];
        int m0 = mcol[p], m1 = mcol[p + 1];
        acc += aA * edge_out2[(size_t)m0 * 16 + c] + aB * edge_out2[(size_t)m1 * 16 + c];
    }
    if (p < end) acc += alpha2[p] * edge_out2[(size_t)mcol[p] * 16 + c];
    int dd = end - beg;
    float D = dd ? 1.0f / (float)dd : 0.0f;
    float v = acc * D + b2[c];
    float mx = v;
    #pragma unroll
    for (int s = 8; s; s >>= 1) mx = fmaxf(mx, __shfl_xor(mx, s));
    float ex = __expf(v - mx);
    float sm = ex;
    #pragma unroll
    for (int s = 8; s; s >>= 1) sm += __shfl_xor(sm, s);
    out[(size_t)n * 16 + c] = (v - mx) - logf(sm);
}

extern "C" void kernel_launch(void* const* d_in, const int* in_sizes, int n_in,
                              void* d_out, int out_size, void* d_ws, size_t ws_size,
                              hipStream_t stream) {
    const float* x        = (const float*)d_in[0];
    const int*   node_idx = (const int*)d_in[1];
    const int*   hedge_idx= (const int*)d_in[2];
    const float* W1       = (const float*)d_in[3];
    const float* att1     = (const float*)d_in[4];
    const float* b1       = (const float*)d_in[5];
    const float* W2       = (const float*)d_in[6];
    const float* att2     = (const float*)d_in[7];
    const float* b2       = (const float*)d_in[8];
    float* out = (float*)d_out;

    char* w = (char*)d_ws;
    auto carve = [&](size_t bytes) -> char* {
        char* p = w;
        w += (bytes + 255) & ~(size_t)255;
        return p;
    };
    int* deg_node  = (int*)carve((size_t)NN * 4);
    int* deg_hedge = (int*)carve((size_t)NM * 4);
    int* cnt_node  = (int*)carve((size_t)NN * 4);
    int* cnt_hedge = (int*)carve((size_t)NM * 4);
    char* zero_end = w;
    int* node_off  = (int*)carve((size_t)(NN + 1) * 4);
    int* hedge_off = (int*)carve((size_t)(NM + 1) * 4);
    int* bsum_n    = (int*)carve(64 * 4);
    int* bsum_h    = (int*)carve(64 * 4);
    int* mcol      = (int*)carve((size_t)NE * 4);
    int* ncol      = (int*)carve((size_t)NE * 4);
    int* pnh       = (int*)carve((size_t)NE * 4);
    unsigned short* W1t = (unsigned short*)carve((size_t)256 * 256 * 2);
    unsigned short* xl  = (unsigned short*)carve((size_t)NN * CD * 2);
    float* sns     = (float*)carve((size_t)NN * 16 * 4);
    float* alpha_csr = (float*)carve((size_t)NE * 8 * 4);
    unsigned short* edge_out = (unsigned short*)carve((size_t)NM * CD * 2);
    float* xl2     = (float*)carve((size_t)NN * C2 * 4);
    float2* sns2   = (float2*)carve((size_t)NN * 8);
    float* alpha2  = (float*)carve((size_t)NE * 4);
    float* edge_out2 = (float*)carve((size_t)NM * C2 * 4);

    hipMemsetAsync(d_ws, 0, (size_t)(zero_end - (char*)d_ws), stream);

    convW1_kernel<<<256, 256, 0, stream>>>(W1, W1t);
    count_deg_kernel<<<CDIV(NE, 256), 256, 0, stream>>>(node_idx, hedge_idx, deg_node, deg_hedge);

    int nbN = CDIV(NN, 1024), nbM = CDIV(NM, 1024);
    scan1_kernel<<<nbN, 1024, 0, stream>>>(deg_node, node_off, bsum_n, NN);
    scan2_kernel<<<1, 64, 0, stream>>>(bsum_n, nbN, node_off + NN);
    scan3_kernel<<<nbN, 1024, 0, stream>>>(node_off, bsum_n, NN);
    scan1_kernel<<<nbM, 1024, 0, stream>>>(deg_hedge, hedge_off, bsum_h, NM);
    scan2_kernel<<<1, 64, 0, stream>>>(bsum_h, nbM, hedge_off + NM);
    scan3_kernel<<<nbM, 1024, 0, stream>>>(hedge_off, bsum_h, NM);

    fill_kernel<<<CDIV(NE, 256), 256, 0, stream>>>(node_idx, hedge_idx, node_off, hedge_off,
                                                   cnt_node, cnt_hedge, mcol, ncol, pnh);

    // ---- conv1 ----
    gemm256_mfma<<<CDIV(NN, 64), 256, 0, stream>>>(x, W1t, att1, xl, sns, NN);
    hedge_fused1<<<NM, 256, 0, stream>>>(xl, sns, ncol, pnh, hedge_off, alpha_csr, edge_out);

    // ---- conv1 node agg + conv2 GEMM fused ----
    node_conv2_fused<<<CDIV(NN, 16), 256, 0, stream>>>(edge_out, alpha_csr, mcol, node_off,
                                                       b1, W2, att2, xl2, sns2);

    // ---- conv2 ----
    hedge_fused2<<<NM, 256, 0, stream>>>(xl2, sns2, ncol, pnh, hedge_off, alpha2, edge_out2);
    node_out2b<<<CDIV(NN, 16), 256, 0, stream>>>(edge_out2, alpha2, mcol, node_off, b2, out);
}

// Round 6
// 249.557 us; speedup vs baseline: 3.8659x; 1.1253x over previous
//
#include <hip/hip_runtime.h>
#include <hip/hip_bf16.h>
#include <math.h>

#define NN 50000
#define NM 10000
#define NE 400000
#define CD 256
#define C2 16

#define CDIV(a,b) (((a)+(b)-1)/(b))
#define NB_GEMM ((NN + 63) / 64)     // 782
#define NB_EDGE ((NE + 255) / 256)   // 1563
#define NBN ((NN + 1023) / 1024)     // 49
#define NBM ((NM + 1023) / 1024)     // 10

typedef __attribute__((ext_vector_type(8))) short short8v;
typedef __attribute__((ext_vector_type(8))) unsigned short ushort8v;
typedef __attribute__((ext_vector_type(4))) float f32x4;

__device__ __forceinline__ float bflo(unsigned int u) { return __uint_as_float(u << 16); }
__device__ __forceinline__ float bfhi(unsigned int u) { return __uint_as_float(u & 0xffff0000u); }
__device__ __forceinline__ unsigned short f2bf(float f) {
    union { __hip_bfloat16 h; unsigned short u; } cv;
    cv.h = __float2bfloat16(f);
    return cv.u;
}
__device__ __forceinline__ unsigned int packbf2(float a, float b) {
    return (unsigned int)f2bf(a) | ((unsigned int)f2bf(b) << 16);
}
__device__ __forceinline__ float bf1(unsigned short u) { return __uint_as_float(((unsigned int)u) << 16); }
__device__ __forceinline__ float lrelu(float s) { return s > 0.f ? s : 0.2f * s; }

// ---------------- prep: convW1 (blocks 0..255) + count_deg (rest) ----------------
__global__ __launch_bounds__(256) void prep_kernel(const float* __restrict__ W1,
        unsigned short* __restrict__ W1t,
        const int* __restrict__ node_idx, const int* __restrict__ hedge_idx,
        int* __restrict__ deg_node, int* __restrict__ deg_hedge) {
    int b = blockIdx.x, t = threadIdx.x;
    if (b < 256) {
        W1t[b * 256 + t] = f2bf(W1[t * 256 + b]);
    } else {
        int e = (b - 256) * 256 + t;
        if (e < NE) {
            atomicAdd(&deg_node[node_idx[e]], 1);
            atomicAdd(&deg_hedge[hedge_idx[e]], 1);
        }
    }
}

// ---------------- scans (node blocks then hedge blocks) ----------------
__global__ __launch_bounds__(1024) void scanA_kernel(const int* __restrict__ deg_n,
        int* __restrict__ off_n, int* __restrict__ bsum_n,
        const int* __restrict__ deg_h, int* __restrict__ off_h, int* __restrict__ bsum_h) {
    __shared__ int lds[1024];
    int t = threadIdx.x, b = blockIdx.x;
    const int* deg; int* off; int* bsum; int n; int lb;
    if (b < NBN) { deg = deg_n; off = off_n; bsum = bsum_n; n = NN; lb = b; }
    else { deg = deg_h; off = off_h; bsum = bsum_h; n = NM; lb = b - NBN; }
    int i = lb * 1024 + t;
    int v = (i < n) ? deg[i] : 0;
    lds[t] = v;
    __syncthreads();
    for (int s = 1; s < 1024; s <<= 1) {
        int tv = (t >= s) ? lds[t - s] : 0;
        __syncthreads();
        lds[t] += tv;
        __syncthreads();
    }
    if (i < n) off[i] = lds[t] - v;
    if (t == 1023) bsum[lb] = lds[t];
}

__global__ void scanB_kernel(int* __restrict__ bsum_n, int* __restrict__ off_n_last,
                             int* __restrict__ bsum_h, int* __restrict__ off_h_last) {
    __shared__ int s[64];
    int t = threadIdx.x;
    int* bsum; int* last; int nb;
    if (blockIdx.x == 0) { bsum = bsum_n; last = off_n_last; nb = NBN; }
    else { bsum = bsum_h; last = off_h_last; nb = NBM; }
    if (t < nb) s[t] = bsum[t];
    __syncthreads();
    if (t == 0) {
        int run = 0;
        for (int j = 0; j < nb; ++j) { int tmp = s[j]; s[j] = run; run += tmp; }
        *last = run;
    }
    __syncthreads();
    if (t < nb) bsum[t] = s[t];
}

__global__ __launch_bounds__(1024) void scanC_kernel(int* __restrict__ off_n,
        const int* __restrict__ bsum_n, int* __restrict__ off_h, const int* __restrict__ bsum_h) {
    int b = blockIdx.x, t = threadIdx.x;
    if (b < NBN) {
        int i = b * 1024 + t;
        if (i < NN) off_n[i] += bsum_n[b];
    } else {
        int i = (b - NBN) * 1024 + t;
        if (i < NM) off_h[i] += bsum_h[b - NBN];
    }
}

// ---------------- fused MFMA GEMM (blocks 0..NB_GEMM-1) + CSR fill (rest) ----------------
// GEMM: xl(bf16)[R,256] = A(f32)[R,256] @ W1; fused sn+snh into sns[R,16]
// fill: mcol[p]=m (4B scatter), nq[q]={n,p} (8B scatter)
__global__ __launch_bounds__(256) void gemm_fill(const float* __restrict__ A,
        const unsigned short* __restrict__ Bt, const float* __restrict__ att1,
        unsigned short* __restrict__ Cbf, float* __restrict__ sns, int R,
        const int* __restrict__ node_idx, const int* __restrict__ hedge_idx,
        const int* __restrict__ node_off, const int* __restrict__ hedge_off,
        int* __restrict__ cnt_node, int* __restrict__ cnt_hedge,
        int* __restrict__ mcol, int2* __restrict__ nq) {
    __shared__ float smem[8512];                             // 34 KB
    int t = threadIdx.x;
    if ((int)blockIdx.x >= NB_GEMM) {
        int e = ((int)blockIdx.x - NB_GEMM) * 256 + t;
        if (e < NE) {
            int n = node_idx[e];
            int m = hedge_idx[e];
            int p = node_off[n] + atomicAdd(&cnt_node[n], 1);
            int q = hedge_off[m] + atomicAdd(&cnt_hedge[m], 1);
            mcol[p] = m;
            nq[q] = make_int2(n, p);
        }
        return;
    }
    unsigned short* As = (unsigned short*)smem;              // [64][40]
    unsigned short* Bs = (unsigned short*)(smem + 1280);     // [256][40]
    int row0 = blockIdx.x * 64;
    int lane = t & 63, wave = t >> 6;
    int wrow = (wave >> 1) * 32, wcol = (wave & 1) * 128;
    int quad = lane >> 4, l15 = lane & 15;
    f32x4 acc[2][8] = {};
    for (int k0 = 0; k0 < 256; k0 += 32) {
        #pragma unroll
        for (int p = 0; p < 2; ++p) {
            int li = t + p * 256;
            int r = li >> 3, kq = li & 7;
            float4 x4 = make_float4(0.f, 0.f, 0.f, 0.f);
            if (row0 + r < R) x4 = *(const float4*)&A[(size_t)(row0 + r) * 256 + k0 + kq * 4];
            ushort4 u;
            u.x = f2bf(x4.x); u.y = f2bf(x4.y); u.z = f2bf(x4.z); u.w = f2bf(x4.w);
            *(ushort4*)&As[r * 40 + kq * 4] = u;
        }
        #pragma unroll
        for (int p = 0; p < 4; ++p) {
            int li = t + p * 256;
            int c = li >> 2, q = li & 3;
            *(ushort8v*)&Bs[c * 40 + q * 8] = *(const ushort8v*)&Bt[(size_t)c * 256 + k0 + q * 8];
        }
        __syncthreads();
        short8v a[2], b[8];
        #pragma unroll
        for (int mi = 0; mi < 2; ++mi)
            a[mi] = *(const short8v*)&As[(wrow + mi * 16 + l15) * 40 + quad * 8];
        #pragma unroll
        for (int ni = 0; ni < 8; ++ni)
            b[ni] = *(const short8v*)&Bs[(wcol + ni * 16 + l15) * 40 + quad * 8];
        #pragma unroll
        for (int mi = 0; mi < 2; ++mi)
            #pragma unroll
            for (int ni = 0; ni < 8; ++ni)
                acc[mi][ni] = __builtin_amdgcn_mfma_f32_16x16x32_bf16(a[mi], b[ni], acc[mi][ni], 0, 0, 0);
        __syncthreads();
    }
    for (int half = 0; half < 2; ++half) {
        if ((wave & 1) == half) {
            #pragma unroll
            for (int mi = 0; mi < 2; ++mi)
                #pragma unroll
                for (int ni = 0; ni < 8; ++ni)
                    #pragma unroll
                    for (int rg = 0; rg < 4; ++rg)
                        smem[(wrow + mi * 16 + quad * 4 + rg) * 133 + ni * 16 + l15] = acc[mi][ni][rg];
        }
        __syncthreads();
        {
            int r = t & 63, hd = t >> 6;
            int hgl = half * 4 + hd;
            float psn = 0.f, psh = 0.f;
            #pragma unroll
            for (int j = 0; j < 32; ++j) {
                float cv = smem[r * 133 + hd * 32 + j];
                psn += cv * att1[hgl * 64 + j];
                psh += cv * att1[hgl * 64 + 32 + j];
            }
            if (row0 + r < R) {
                sns[(size_t)(row0 + r) * 16 + hgl] = psn;
                sns[(size_t)(row0 + r) * 16 + 8 + hgl] = psh;
            }
        }
        {
            int r2 = t >> 2, c0 = (t & 3) * 32;
            if (row0 + r2 < R) {
                unsigned int buf[16];
                #pragma unroll
                for (int j = 0; j < 16; ++j)
                    buf[j] = packbf2(smem[r2 * 133 + c0 + 2 * j], smem[r2 * 133 + c0 + 2 * j + 1]);
                size_t base = (size_t)(row0 + r2) * 256 + half * 128 + c0;
                *(ushort8v*)&Cbf[base]      = *(ushort8v*)&buf[0];
                *(ushort8v*)&Cbf[base + 8]  = *(ushort8v*)&buf[4];
                *(ushort8v*)&Cbf[base + 16] = *(ushort8v*)&buf[8];
                *(ushort8v*)&Cbf[base + 24] = *(ushort8v*)&buf[12];
            }
        }
        __syncthreads();
    }
}

// ---------------- conv1 fused per-hedge ----------------
__global__ __launch_bounds__(256) void hedge_fused1(const unsigned short* __restrict__ xl,
        const float* __restrict__ sns,
        const int2* __restrict__ nq, const int* __restrict__ offs,
        float* __restrict__ alpha_csr, unsigned short* __restrict__ edge_out) {
    __shared__ int nl[1024];
    __shared__ float ssc[2048];     // [256 rows][8 heads]; later aliased as pass-B reduce
    __shared__ float red[256];
    __shared__ float redH[512];     // [64 slots][8 heads]
    __shared__ float shv8[8], mh8[8], inv8[8];
    int m = blockIdx.x;
    int beg = offs[m], d = offs[m + 1] - beg;
    int t = threadIdx.x;
    for (int i = t; i < d; i += 256) nl[i] = nq[beg + i].x;
    __syncthreads();
    // ---- pass 0: merged sns sweep ----
    {
        int q = t & 3, i0 = t >> 2;   // 64 rows in parallel, 4 threads/row (16B each)
        float4 hs = make_float4(0.f, 0.f, 0.f, 0.f);
        for (int i = i0; i < d; i += 64) {
            float4 v = *(const float4*)&sns[(size_t)nl[i] * 16 + q * 4];
            if (q < 2) {
                if (i < 256) *(float4*)&ssc[i * 8 + q * 4] = v;
            } else {
                hs.x += v.x; hs.y += v.y; hs.z += v.z; hs.w += v.w;
            }
        }
        if (q >= 2) *(float4*)&redH[(i0 * 8) + (q - 2) * 4] = hs;
    }
    __syncthreads();
    if (t < 256) redH[t] += redH[t + 256];
    __syncthreads();
    for (int s = 128; s >= 8; s >>= 1) {
        if (t < s) redH[t] += redH[t + s];
        __syncthreads();
    }
    if (t < 8) shv8[t] = redH[t];
    __syncthreads();
    int h = t & 7, sl = t >> 3;
    float shvh = shv8[h];
    // ---- max ----
    float pm = -1e30f;
    for (int i = sl; i < d; i += 32) {
        float sv = (i < 256) ? ssc[i * 8 + h] : sns[(size_t)nl[i] * 16 + h];
        float s = lrelu(sv + shvh);
        if (i < 256) ssc[i * 8 + h] = s;
        pm = fmaxf(pm, s);
    }
    red[t] = pm; __syncthreads();
    for (int s2 = 16; s2; s2 >>= 1) { if (sl < s2) red[t] = fmaxf(red[t], red[t + s2 * 8]); __syncthreads(); }
    if (t < 8) mh8[t] = red[t];
    __syncthreads();
    float mh = mh8[h];
    // ---- exp-sum ----
    float ps = 0.f;
    for (int i = sl; i < d; i += 32) {
        float s = (i < 256) ? ssc[i * 8 + h] : lrelu(sns[(size_t)nl[i] * 16 + h] + shvh);
        float e = __expf(s - mh);
        if (i < 256) ssc[i * 8 + h] = e;
        ps += e;
    }
    red[t] = ps; __syncthreads();
    for (int s2 = 16; s2; s2 >>= 1) { if (sl < s2) red[t] += red[t + s2 * 8]; __syncthreads(); }
    if (t < 8) inv8[t] = 1.0f / (red[t] + 1e-16f);
    __syncthreads();
    float iv = inv8[h];
    // ---- alpha scatter to node-CSR ----
    for (int i = sl; i < d; i += 32) {
        float a;
        if (i < 256) { a = ssc[i * 8 + h] * iv; ssc[i * 8 + h] = a; }
        else a = __expf(lrelu(sns[(size_t)nl[i] * 16 + h] + shvh) - mh) * iv;
        alpha_csr[(size_t)nq[beg + i].y * 8 + h] = a;
    }
    __syncthreads();
    // ---- pass B: weighted xl gather ----
    int lane32 = t & 31, rs8 = t >> 5;
    int c8 = lane32 * 8;
    int hh = lane32 >> 2;
    float mh2 = mh8[hh], iv2 = inv8[hh], sv2 = shv8[hh];
    float acc8[8] = {};
    int i = rs8;
    for (; i + 8 < d; i += 16) {
        int n0 = nl[i], n1 = nl[i + 8];
        float aA = (i < 256) ? ssc[i * 8 + hh]
                 : __expf(lrelu(sns[(size_t)n0 * 16 + hh] + sv2) - mh2) * iv2;
        float aB = (i + 8 < 256) ? ssc[(i + 8) * 8 + hh]
                 : __expf(lrelu(sns[(size_t)n1 * 16 + hh] + sv2) - mh2) * iv2;
        ushort8v uA = *(const ushort8v*)&xl[(size_t)n0 * 256 + c8];
        ushort8v uB = *(const ushort8v*)&xl[(size_t)n1 * 256 + c8];
        #pragma unroll
        for (int j = 0; j < 8; ++j)
            acc8[j] += aA * bf1((unsigned short)uA[j]) + aB * bf1((unsigned short)uB[j]);
    }
    for (; i < d; i += 8) {
        int n0 = nl[i];
        float aA = (i < 256) ? ssc[i * 8 + hh]
                 : __expf(lrelu(sns[(size_t)n0 * 16 + hh] + sv2) - mh2) * iv2;
        ushort8v uA = *(const ushort8v*)&xl[(size_t)n0 * 256 + c8];
        #pragma unroll
        for (int j = 0; j < 8; ++j)
            acc8[j] += aA * bf1((unsigned short)uA[j]);
    }
    __syncthreads();
    float* redA = ssc;
    *(float4*)&redA[t * 8]     = make_float4(acc8[0], acc8[1], acc8[2], acc8[3]);
    *(float4*)&redA[t * 8 + 4] = make_float4(acc8[4], acc8[5], acc8[6], acc8[7]);
    __syncthreads();
    for (int s = 4; s >= 1; s >>= 1) {
        if (rs8 < s) {
            #pragma unroll
            for (int j = 0; j < 8; ++j) redA[t * 8 + j] += redA[(t + s * 32) * 8 + j];
        }
        __syncthreads();
    }
    if (t < 32) {
        float Bv = d ? 1.0f / (float)d : 0.0f;
        unsigned int buf[4];
        #pragma unroll
        for (int j = 0; j < 4; ++j)
            buf[j] = packbf2(redA[t * 8 + 2 * j] * Bv, redA[t * 8 + 2 * j + 1] * Bv);
        *(ushort8v*)&edge_out[(size_t)m * 256 + t * 8] = *(ushort8v*)&buf[0];
    }
}

// ---------------- fused conv1-node-agg + conv2 GEMM: 16 nodes/block ----------------
#define ALS 264
__global__ __launch_bounds__(256) void node_conv2_fused(const unsigned short* __restrict__ edge_out,
        const float* __restrict__ alpha_csr, const int* __restrict__ mcol,
        const int* __restrict__ offs, const float* __restrict__ b1,
        const float* __restrict__ W2, const float* __restrict__ att2,
        float* __restrict__ xl2, float2* __restrict__ sns2) {
    __shared__ float W2L[4096];
    __shared__ unsigned short AL[16 * ALS];
    __shared__ float b1L[256];
    int t = threadIdx.x;
    for (int i = t; i < 4096; i += 256) W2L[i] = W2[i];
    if (t < 256) b1L[t] = b1[t];
    int r = t >> 4, c = t & 15;
    int n = blockIdx.x * 16 + r;
    int beg = offs[n], end = offs[n + 1];
    int h = c >> 1;
    float acc[16] = {};
    int p = beg;
    for (; p + 3 < end; p += 4) {
        float aA = alpha_csr[(size_t)p * 8 + h];
        float aB = alpha_csr[(size_t)(p + 1) * 8 + h];
        float aC = alpha_csr[(size_t)(p + 2) * 8 + h];
        float aD = alpha_csr[(size_t)(p + 3) * 8 + h];
        int m0 = mcol[p], m1 = mcol[p + 1], m2 = mcol[p + 2], m3 = mcol[p + 3];
        ushort8v u0a = *(const ushort8v*)&edge_out[(size_t)m0 * 256 + c * 16];
        ushort8v u0b = *(const ushort8v*)&edge_out[(size_t)m0 * 256 + c * 16 + 8];
        ushort8v u1a = *(const ushort8v*)&edge_out[(size_t)m1 * 256 + c * 16];
        ushort8v u1b = *(const ushort8v*)&edge_out[(size_t)m1 * 256 + c * 16 + 8];
        ushort8v u2a = *(const ushort8v*)&edge_out[(size_t)m2 * 256 + c * 16];
        ushort8v u2b = *(const ushort8v*)&edge_out[(size_t)m2 * 256 + c * 16 + 8];
        ushort8v u3a = *(const ushort8v*)&edge_out[(size_t)m3 * 256 + c * 16];
        ushort8v u3b = *(const ushort8v*)&edge_out[(size_t)m3 * 256 + c * 16 + 8];
        #pragma unroll
        for (int j = 0; j < 8; ++j) {
            acc[j]     += aA * bf1((unsigned short)u0a[j]) + aB * bf1((unsigned short)u1a[j])
                        + aC * bf1((unsigned short)u2a[j]) + aD * bf1((unsigned short)u3a[j]);
            acc[j + 8] += aA * bf1((unsigned short)u0b[j]) + aB * bf1((unsigned short)u1b[j])
                        + aC * bf1((unsigned short)u2b[j]) + aD * bf1((unsigned short)u3b[j]);
        }
    }
    for (; p < end; ++p) {
        float aA = alpha_csr[(size_t)p * 8 + h];
        int m0 = mcol[p];
        ushort8v u0a = *(const ushort8v*)&edge_out[(size_t)m0 * 256 + c * 16];
        ushort8v u0b = *(const ushort8v*)&edge_out[(size_t)m0 * 256 + c * 16 + 8];
        #pragma unroll
        for (int j = 0; j < 8; ++j) {
            acc[j]     += aA * bf1((unsigned short)u0a[j]);
            acc[j + 8] += aA * bf1((unsigned short)u0b[j]);
        }
    }
    __syncthreads();
    int dd = end - beg;
    float D = dd ? 1.0f / (float)dd : 0.0f;
    {
        unsigned short tmp[16];
        #pragma unroll
        for (int j = 0; j < 16; ++j) {
            float v = acc[j] * D + b1L[c * 16 + j];
            tmp[j] = f2bf(v > 0.f ? v : 0.f);
        }
        *(ushort8v*)&AL[r * ALS + c * 16]     = *(ushort8v*)&tmp[0];
        *(ushort8v*)&AL[r * ALS + c * 16 + 8] = *(ushort8v*)&tmp[8];
    }
    __syncthreads();
    float acc2 = 0.f;
    for (int k = 0; k < 256; k += 4) {
        ushort4 av = *(const ushort4*)&AL[r * ALS + k];
        acc2 += bf1(av.x) * W2L[k * 16 + c] + bf1(av.y) * W2L[(k + 1) * 16 + c]
              + bf1(av.z) * W2L[(k + 2) * 16 + c] + bf1(av.w) * W2L[(k + 3) * 16 + c];
    }
    float svn = acc2 * att2[c];
    float svh = acc2 * att2[16 + c];
    #pragma unroll
    for (int s = 8; s; s >>= 1) { svn += __shfl_xor(svn, s); svh += __shfl_xor(svh, s); }
    xl2[(size_t)n * 16 + c] = acc2;
    if (c == 0) sns2[n] = make_float2(svn, svh);
}

// ---------------- conv2 fused per-hedge ----------------
__global__ __launch_bounds__(256) void hedge_fused2(const float* __restrict__ xl2,
        const float2* __restrict__ sns2,
        const int2* __restrict__ nq, const int* __restrict__ offs,
        float* __restrict__ alpha2, float* __restrict__ edge_out2) {
    __shared__ int nl[1024];
    __shared__ float ssc[1024];
    __shared__ float red[256];
    __shared__ float sh_s, mh_s, inv_s;
    int m = blockIdx.x;
    int beg = offs[m], d = offs[m + 1] - beg;
    int t = threadIdx.x;
    for (int i = t; i < d; i += 256) nl[i] = nq[beg + i].x;
    __syncthreads();
    float sv = 0.f;
    for (int i = t; i < d; i += 256) {
        float2 v = sns2[nl[i]];
        ssc[i] = v.x;
        sv += v.y;
    }
    red[t] = sv; __syncthreads();
    for (int s2 = 128; s2; s2 >>= 1) { if (t < s2) red[t] += red[t + s2]; __syncthreads(); }
    if (t == 0) sh_s = red[0];
    __syncthreads();
    float sh = sh_s;
    float pm = -1e30f;
    for (int i = t; i < d; i += 256) {
        float s = lrelu(ssc[i] + sh);
        ssc[i] = s;
        pm = fmaxf(pm, s);
    }
    red[t] = pm; __syncthreads();
    for (int s2 = 128; s2; s2 >>= 1) { if (t < s2) red[t] = fmaxf(red[t], red[t + s2]); __syncthreads(); }
    if (t == 0) mh_s = red[0];
    __syncthreads();
    float mh = mh_s;
    float ps = 0.f;
    for (int i = t; i < d; i += 256) ps += __expf(ssc[i] - mh);
    red[t] = ps; __syncthreads();
    for (int s2 = 128; s2; s2 >>= 1) { if (t < s2) red[t] += red[t + s2]; __syncthreads(); }
    if (t == 0) inv_s = 1.0f / (red[0] + 1e-16f);
    __syncthreads();
    float inv = inv_s;
    for (int i = t; i < d; i += 256) {
        float a = __expf(ssc[i] - mh) * inv;
        ssc[i] = a;
        alpha2[nq[beg + i].y] = a;
    }
    __syncthreads();
    int ip = t >> 4, c = t & 15;
    float acc = 0.f;
    for (int i = ip; i < d; i += 16) acc += ssc[i] * xl2[(size_t)nl[i] * 16 + c];
    red[t] = acc; __syncthreads();
    for (int s2 = 8; s2; s2 >>= 1) { if (ip < s2) red[t] += red[t + s2 * 16]; __syncthreads(); }
    if (t < 16) {
        float Bv = d ? 1.0f / (float)d : 0.0f;
        edge_out2[(size_t)m * 16 + t] = red[t] * Bv;
    }
}

// ---------------- conv2 node aggregation + log_softmax: 16 nodes/block ----------------
__global__ __launch_bounds__(256) void node_out2b(const float* __restrict__ edge_out2,
        const float* __restrict__ alpha2, const int* __restrict__ mcol,
        const int* __restrict__ offs, const float* __restrict__ b2, float* __restrict__ out) {
    int t = threadIdx.x;
    int n = blockIdx.x * 16 + (t >> 4);
    int c = t & 15;
    int beg = offs[n], end = offs[n + 1];
    float acc = 0.f;
    int p = beg;
    for (; p + 1 < end; p += 2) {
        float aA = alpha2[p], aB = alpha2[p + 1];
        int m0 = mcol[p], m1 = mcol[p + 1];
        acc += aA * edge_out2[(size_t)m0 * 16 + c] + aB * edge_out2[(size_t)m1 * 16 + c];
    }
    if (p < end) acc += alpha2[p] * edge_out2[(size_t)mcol[p] * 16 + c];
    int dd = end - beg;
    float D = dd ? 1.0f / (float)dd : 0.0f;
    float v = acc * D + b2[c];
    float mx = v;
    #pragma unroll
    for (int s = 8; s; s >>= 1) mx = fmaxf(mx, __shfl_xor(mx, s));
    float ex = __expf(v - mx);
    float sm = ex;
    #pragma unroll
    for (int s = 8; s; s >>= 1) sm += __shfl_xor(sm, s);
    out[(size_t)n * 16 + c] = (v - mx) - logf(sm);
}

extern "C" void kernel_launch(void* const* d_in, const int* in_sizes, int n_in,
                              void* d_out, int out_size, void* d_ws, size_t ws_size,
                              hipStream_t stream) {
    const float* x        = (const float*)d_in[0];
    const int*   node_idx = (const int*)d_in[1];
    const int*   hedge_idx= (const int*)d_in[2];
    const float* W1       = (const float*)d_in[3];
    const float* att1     = (const float*)d_in[4];
    const float* b1       = (const float*)d_in[5];
    const float* W2       = (const float*)d_in[6];
    const float* att2     = (const float*)d_in[7];
    const float* b2       = (const float*)d_in[8];
    float* out = (float*)d_out;

    char* w = (char*)d_ws;
    auto carve = [&](size_t bytes) -> char* {
        char* p = w;
        w += (bytes + 255) & ~(size_t)255;
        return p;
    };
    int* deg_node  = (int*)carve((size_t)NN * 4);
    int* deg_hedge = (int*)carve((size_t)NM * 4);
    int* cnt_node  = (int*)carve((size_t)NN * 4);
    int* cnt_hedge = (int*)carve((size_t)NM * 4);
    char* zero_end = w;
    int* node_off  = (int*)carve((size_t)(NN + 1) * 4);
    int* hedge_off = (int*)carve((size_t)(NM + 1) * 4);
    int* bsum_n    = (int*)carve(64 * 4);
    int* bsum_h    = (int*)carve(64 * 4);
    int* mcol      = (int*)carve((size_t)NE * 4);
    int2* nq       = (int2*)carve((size_t)NE * 8);
    unsigned short* W1t = (unsigned short*)carve((size_t)256 * 256 * 2);
    unsigned short* xl  = (unsigned short*)carve((size_t)NN * CD * 2);
    float* sns     = (float*)carve((size_t)NN * 16 * 4);
    float* alpha_csr = (float*)carve((size_t)NE * 8 * 4);
    unsigned short* edge_out = (unsigned short*)carve((size_t)NM * CD * 2);
    float* xl2     = (float*)carve((size_t)NN * C2 * 4);
    float2* sns2   = (float2*)carve((size_t)NN * 8);
    float* alpha2  = (float*)carve((size_t)NE * 4);
    float* edge_out2 = (float*)carve((size_t)NM * C2 * 4);

    hipMemsetAsync(d_ws, 0, (size_t)(zero_end - (char*)d_ws), stream);

    prep_kernel<<<256 + NB_EDGE, 256, 0, stream>>>(W1, W1t, node_idx, hedge_idx,
                                                   deg_node, deg_hedge);

    scanA_kernel<<<NBN + NBM, 1024, 0, stream>>>(deg_node, node_off, bsum_n,
                                                 deg_hedge, hedge_off, bsum_h);
    scanB_kernel<<<2, 64, 0, stream>>>(bsum_n, node_off + NN, bsum_h, hedge_off + NM);
    scanC_kernel<<<NBN + NBM, 1024, 0, stream>>>(node_off, bsum_n, hedge_off, bsum_h);

    // ---- conv1 GEMM + CSR fill (independent, grid-fused) ----
    gemm_fill<<<NB_GEMM + NB_EDGE, 256, 0, stream>>>(x, W1t, att1, xl, sns, NN,
                                                     node_idx, hedge_idx, node_off, hedge_off,
                                                     cnt_node, cnt_hedge, mcol, nq);

    hedge_fused1<<<NM, 256, 0, stream>>>(xl, sns, nq, hedge_off, alpha_csr, edge_out);
    node_conv2_fused<<<CDIV(NN, 16), 256, 0, stream>>>(edge_out, alpha_csr, mcol, node_off,
                                                       b1, W2, att2, xl2, sns2);
    hedge_fused2<<<NM, 256, 0, stream>>>(xl2, sns2, nq, hedge_off, alpha2, edge_out2);
    node_out2b<<<CDIV(NN, 16), 256, 0, stream>>>(edge_out2, alpha2, mcol, node_off, b2, out);
}